// Round 10
// baseline (1598.748 us; speedup 1.0000x reference)
//
#include <hip/hip_runtime.h>

typedef unsigned short u16;
typedef unsigned int   u32;
typedef unsigned long long u64;
typedef __attribute__((ext_vector_type(8))) short s8v;   // 8 bf16 (4 VGPRs) MFMA operand
typedef __attribute__((ext_vector_type(4))) float f4v;   // MFMA accumulator

#define NN 20000
#define EE 320000
#define BB 128
#define HH 256

union BU { u64 d[2]; s8v v; };

__device__ __forceinline__ u16 f2bf(float f){
  u32 u = __float_as_uint(f);
  return (u16)((u + 0x7FFFu + ((u >> 16) & 1u)) >> 16);   // RNE
}
__device__ __forceinline__ float bf2f(u16 u){ return __uint_as_float((u32)u << 16); }
__device__ __forceinline__ u32 cvt2(float a, float b){
  u32 r; asm("v_cvt_pk_bf16_f32 %0, %1, %2" : "=v"(r) : "v"(a), "v"(b)); return r;
}
__device__ __forceinline__ u64 pack4bf(float a, float b, float c, float d){
  return (u64)cvt2(a, b) | ((u64)cvt2(c, d) << 32);
}
__device__ __forceinline__ float4 up4(u64 v){
  return make_float4(bf2f((u16)v), bf2f((u16)(v >> 16)), bf2f((u16)(v >> 32)), bf2f((u16)(v >> 48)));
}
// silu via v_rcp (1 instr); 1-ulp rcp error << bf16 rounding
__device__ __forceinline__ float siluf(float v){
  return v * __builtin_amdgcn_rcpf(1.0f + __expf(-v));
}

// ---------------- weight packing: W [K][256] f32 -> A-fragment blob (W^T), bf16 ----------------
// remap=1 (edge_w1): new-k 512..527 <- old 513..528 (eattr), new-k 528 <- old 512 (radial)
__global__ void pack_kernel(const float* __restrict__ src, u16* __restrict__ dst, int K, int KB, int remap){
  int t = blockIdx.x * 256 + threadIdx.x;
  if (t >= KB * 1024) return;
  int lane = t & 63, mf = (t >> 6) & 15, kb = t >> 10;
  int g = lane >> 4, li = lane & 15;
  int m = mf * 16 + li;
  u16 o[8];
  #pragma unroll
  for (int j = 0; j < 8; ++j){
    int k = kb * 32 + ((j < 4) ? (g * 4 + j) : (16 + g * 4 + (j - 4)));
    int ks = k;
    if (remap){ if (k >= 512 && k < 528) ks = k + 1; else if (k == 528) ks = 512; }
    o[j] = (k < K) ? f2bf(src[(size_t)ks * 256 + m]) : (u16)0;
  }
  u16* d = dst + ((size_t)(kb * 16 + mf) * 64 + lane) * 8;
  *(u64*)(d)     = (u64)o[0] | ((u64)o[1] << 16) | ((u64)o[2] << 32) | ((u64)o[3] << 48);
  *(u64*)(d + 4) = (u64)o[4] | ((u64)o[5] << 16) | ((u64)o[6] << 32) | ((u64)o[7] << 48);
}

// ---------------- edge sort by destination row (one-time per launch) ----------------
__global__ void icnt_kernel(const int* __restrict__ ei, int* __restrict__ icnt){
  int t = blockIdx.x * 256 + threadIdx.x;
  if (t < EE) atomicAdd(&icnt[ei[t]], 1);
}
__global__ void iscan_block(const int* __restrict__ icnt, int* __restrict__ iscan, int* __restrict__ bsum){
  __shared__ int s[256];
  int i = blockIdx.x * 256 + threadIdx.x;
  int v = (i < NN) ? icnt[i] : 0;
  s[threadIdx.x] = v; __syncthreads();
  #pragma unroll
  for (int d = 1; d < 256; d <<= 1){
    int t = (threadIdx.x >= d) ? s[threadIdx.x - d] : 0;
    __syncthreads();
    s[threadIdx.x] += t;
    __syncthreads();
  }
  if (i < NN) iscan[i] = s[threadIdx.x];
  if (threadIdx.x == 255) bsum[blockIdx.x] = s[255];
}
__global__ void iscan_top(int* __restrict__ bsum, int nb){
  if (blockIdx.x == 0 && threadIdx.x == 0){
    int acc = 0;
    for (int i = 0; i < nb; ++i){ int t = bsum[i]; bsum[i] = acc; acc += t; }
  }
}
__global__ void iscan_fix(const int* __restrict__ icnt, const int* __restrict__ iscan,
                          const int* __restrict__ bsum, int* __restrict__ rstart){
  int i = blockIdx.x * 256 + threadIdx.x;
  if (i < NN) rstart[i] = bsum[blockIdx.x] + iscan[i] - icnt[i];
}
__global__ void scatter_kernel(const int* __restrict__ ei, const int* __restrict__ rstart,
                               int* __restrict__ cursor, int* __restrict__ seid,
                               int* __restrict__ srow, int* __restrict__ scol){
  int e = blockIdx.x * 256 + threadIdx.x;
  if (e < EE){
    int r = ei[e];
    int p = rstart[r] + atomicAdd(&cursor[r], 1);
    seid[p] = e; srow[p] = r; scol[p] = ei[EE + e];
  }
}
// eattr gathered into sorted order, bf16 (one-time)
__global__ void sort_ea_kernel(const float* __restrict__ eattr, const int* __restrict__ seid,
                               u16* __restrict__ es){
  int t = blockIdx.x * 256 + threadIdx.x;
  if (t < EE * 16){
    int p = t >> 4, j = t & 15;
    es[t] = f2bf(eattr[(size_t)seid[p] * 16 + j]);
  }
}
// per-graph node ranges from the SORTED batch array (run once)
__global__ void bstart_kernel(const int* __restrict__ batch, int* __restrict__ bstart){
  int n = blockIdx.x * 256 + threadIdx.x;
  if (n >= NN) return;
  int b = batch[n];
  if (n == 0){ for (int x = 0; x <= b; ++x) bstart[x] = 0; }
  else {
    int pb = batch[n - 1];
    for (int x = pb + 1; x <= b; ++x) bstart[x] = n;
  }
  if (n == NN - 1) bstart[BB] = NN;
}

// ---------------- small utility kernels ----------------
__global__ void coord_init_kernel(const float* __restrict__ pos, float4* __restrict__ coord){
  int t = blockIdx.x * 256 + threadIdx.x;
  if (t < NN) coord[t] = make_float4(pos[3*t], pos[3*t+1], pos[3*t+2], 0.f);
}
__global__ void coord_upd_kernel(float4* __restrict__ coord, const float* __restrict__ cacc,
                                 const int* __restrict__ icnt){
  int t = blockIdx.x * 256 + threadIdx.x;
  if (t >= NN) return;
  float k = fmaxf((float)icnt[t], 1.0f);
  float4 c = coord[t];
  c.x += cacc[4*t+0] / k; c.y += cacc[4*t+1] / k; c.z += cacc[4*t+2] / k;
  coord[t] = c;
}

// ---------------- CSR segment-sum: agg_bf[n][f] = bf16( sum_e m2[e][f] ) ----------------
__global__ __launch_bounds__(256) void agg_csr_kernel(
    const u16* __restrict__ m2b, const int* __restrict__ rstart,
    const int* __restrict__ icnt, u16* __restrict__ agg_bf){
  const int n = blockIdx.x, f = threadIdx.x;
  const int s = rstart[n], d = icnt[n];
  const u16* p = m2b + (size_t)s * 256 + f;
  float a0 = 0.f, a1 = 0.f;
  int i = 0;
  for (; i + 1 < d; i += 2){
    a0 += bf2f(__builtin_nontemporal_load(&p[(size_t)i * 256]));
    a1 += bf2f(__builtin_nontemporal_load(&p[(size_t)(i + 1) * 256]));
  }
  if (i < d) a0 += bf2f(__builtin_nontemporal_load(&p[(size_t)i * 256]));
  agg_bf[(size_t)n * 256 + f] = f2bf(a0 + a1);
}
__global__ void agg_conv_kernel(const float* __restrict__ agg, u16* __restrict__ agg_bf){
  int t = blockIdx.x * 256 + threadIdx.x;
  if (t < NN * HH) agg_bf[t] = f2bf(agg[t]);
}

// ---------------- emb_in (+ fused pab for layer 0) ----------------
// LDS pair layout: chunk c=(a,b4,g) stored as ulonglong2 at mt2[e*32 + ((a*4+g)^(e&7))];
// pbase = e*32 + (g^(e&3)), pm4 = e&4; index(a) = pbase + ((4a)^pm4).
__global__ __launch_bounds__(256) void emb_in_kernel(
    const float* __restrict__ x, const u16* __restrict__ pw,
    const float* __restrict__ bias, float* __restrict__ h, u16* __restrict__ hb,
    const u16* __restrict__ pw1n, const float* __restrict__ b1n,
    u16* __restrict__ Pab, u16* __restrict__ Pbb){
  __shared__ ulonglong2 mt2[2048];
  const int tid = threadIdx.x;
  const int w = tid >> 6, l = tid & 63, g = l >> 4, li = l & 15;
  const int nb = blockIdx.x * 64;
  const float* xp[4];
  int pbase[4], pm4[4];
  #pragma unroll
  for (int nf = 0; nf < 4; ++nf){
    int n = nb + nf * 16 + li; if (n >= NN) n = NN - 1;
    xp[nf] = x + (size_t)n * 128 + g * 4;
    int e = nf * 16 + li;
    pbase[nf] = e * 32 + (g ^ (e & 3));
    pm4[nf] = e & 4;
  }
  f4v acc[4][4];
  #pragma unroll
  for (int a = 0; a < 4; ++a)
    #pragma unroll
    for (int b = 0; b < 4; ++b) acc[a][b] = (f4v){0.f,0.f,0.f,0.f};
  const u16* pwb = pw + ((size_t)(w * 4) * 64 + l) * 8;
  #pragma unroll
  for (int kb = 0; kb < 4; ++kb){
    s8v A[4];
    #pragma unroll
    for (int mf = 0; mf < 4; ++mf) A[mf] = *(const s8v*)(pwb + (size_t)kb * 8192 + mf * 512);
    #pragma unroll
    for (int nf = 0; nf < 4; ++nf){
      float4 fa = *(const float4*)(xp[nf] + kb * 32);
      float4 fb = *(const float4*)(xp[nf] + kb * 32 + 16);
      BU bu;
      bu.d[0] = pack4bf(fa.x, fa.y, fa.z, fa.w);
      bu.d[1] = pack4bf(fb.x, fb.y, fb.z, fb.w);
      #pragma unroll
      for (int mf = 0; mf < 4; ++mf)
        acc[mf][nf] = __builtin_amdgcn_mfma_f32_16x16x32_bf16(A[mf], bu.v, acc[mf][nf], 0, 0, 0);
    }
  }
  u64 pm[4][4];
  #pragma unroll
  for (int mf = 0; mf < 4; ++mf){
    const int fb = w * 64 + mf * 16 + g * 4;
    float b0 = bias[fb], b1 = bias[fb+1], b2 = bias[fb+2], b3 = bias[fb+3];
    #pragma unroll
    for (int nf = 0; nf < 4; ++nf){
      int n = nb + nf * 16 + li;
      float o0 = acc[mf][nf][0] + b0, o1 = acc[mf][nf][1] + b1;
      float o2 = acc[mf][nf][2] + b2, o3 = acc[mf][nf][3] + b3;
      pm[mf][nf] = pack4bf(o0, o1, o2, o3);
      if (n < NN){
        *(float4*)(h + (size_t)n * HH + fb) = make_float4(o0, o1, o2, o3);
        *(u64*)(hb + (size_t)n * HH + fb) = pm[mf][nf];
      }
    }
  }
  #pragma unroll
  for (int nf = 0; nf < 4; ++nf){
    ulonglong2 t0; t0.x = pm[0][nf]; t0.y = pm[1][nf];
    ulonglong2 t1; t1.x = pm[2][nf]; t1.y = pm[3][nf];
    mt2[pbase[nf] + ((8 * w)     ^ pm4[nf])] = t0;
    mt2[pbase[nf] + ((8 * w + 4) ^ pm4[nf])] = t1;
  }
  __syncthreads();
  const u16* pwn = pw1n + ((size_t)(w * 4) * 64 + l) * 8;
  #pragma unroll
  for (int pass = 0; pass < 2; ++pass){
    #pragma unroll
    for (int a = 0; a < 4; ++a)
      #pragma unroll
      for (int b = 0; b < 4; ++b) acc[a][b] = (f4v){0.f,0.f,0.f,0.f};
    const u16* pwp = pwn + (size_t)(pass * 8) * 8192;
    #pragma unroll 4
    for (int kb = 0; kb < 8; ++kb){
      s8v A[4];
      #pragma unroll
      for (int mf = 0; mf < 4; ++mf) A[mf] = *(const s8v*)(pwp + (size_t)kb * 8192 + mf * 512);
      #pragma unroll
      for (int nf = 0; nf < 4; ++nf){
        ulonglong2 pr = mt2[pbase[nf] + ((4 * kb) ^ pm4[nf])];
        BU bu; bu.d[0] = pr.x; bu.d[1] = pr.y;
        #pragma unroll
        for (int mf = 0; mf < 4; ++mf)
          acc[mf][nf] = __builtin_amdgcn_mfma_f32_16x16x32_bf16(A[mf], bu.v, acc[mf][nf], 0, 0, 0);
      }
    }
    u16* dst = pass ? Pbb : Pab;
    #pragma unroll
    for (int mf = 0; mf < 4; ++mf){
      const int fb = w * 64 + mf * 16 + g * 4;
      float c0 = 0.f, c1 = 0.f, c2 = 0.f, c3 = 0.f;
      if (!pass){ c0 = b1n[fb]; c1 = b1n[fb+1]; c2 = b1n[fb+2]; c3 = b1n[fb+3]; }
      #pragma unroll
      for (int nf = 0; nf < 4; ++nf){
        int n = nb + nf * 16 + li;
        if (n < NN)
          *(u64*)(dst + (size_t)n * HH + fb) =
            pack4bf(acc[mf][nf][0] + c0, acc[mf][nf][1] + c1,
                    acc[mf][nf][2] + c2, acc[mf][nf][3] + c3);
      }
    }
  }
}

// ---------------- emb_out: ho = h @ emb_out_w + b ----------------
__global__ __launch_bounds__(256) void emb_out_kernel(
    const u16* __restrict__ hb, const u16* __restrict__ pw,
    const float* __restrict__ bias, float* __restrict__ ho){
  const int tid = threadIdx.x;
  const int w = tid >> 6, l = tid & 63, g = l >> 4, li = l & 15;
  const int nb = blockIdx.x * 64;
  const u16* hp[4];
  #pragma unroll
  for (int nf = 0; nf < 4; ++nf){
    int n = nb + nf * 16 + li; if (n >= NN) n = NN - 1;
    hp[nf] = hb + (size_t)n * HH + g * 4;
  }
  f4v acc[4][4];
  #pragma unroll
  for (int a = 0; a < 4; ++a)
    #pragma unroll
    for (int b = 0; b < 4; ++b) acc[a][b] = (f4v){0.f,0.f,0.f,0.f};
  const u16* pwb = pw + ((size_t)(w * 4) * 64 + l) * 8;
  #pragma unroll 4
  for (int kb = 0; kb < 8; ++kb){
    s8v A[4];
    #pragma unroll
    for (int mf = 0; mf < 4; ++mf) A[mf] = *(const s8v*)(pwb + (size_t)kb * 8192 + mf * 512);
    #pragma unroll
    for (int nf = 0; nf < 4; ++nf){
      BU bu;
      bu.d[0] = *(const u64*)(hp[nf] + kb * 32);
      bu.d[1] = *(const u64*)(hp[nf] + kb * 32 + 16);
      #pragma unroll
      for (int mf = 0; mf < 4; ++mf)
        acc[mf][nf] = __builtin_amdgcn_mfma_f32_16x16x32_bf16(A[mf], bu.v, acc[mf][nf], 0, 0, 0);
    }
  }
  #pragma unroll
  for (int mf = 0; mf < 4; ++mf){
    const int fb = w * 64 + mf * 16 + g * 4;
    float b0 = bias[fb], b1 = bias[fb+1], b2 = bias[fb+2], b3 = bias[fb+3];
    #pragma unroll
    for (int nf = 0; nf < 4; ++nf){
      int n = nb + nf * 16 + li;
      if (n < NN)
        *(float4*)(ho + (size_t)n * HH + fb) =
          make_float4(acc[mf][nf][0] + b0, acc[mf][nf][1] + b1,
                      acc[mf][nf][2] + b2, acc[mf][nf][3] + b3);
    }
  }
}

// ---------------- max-pool over contiguous per-graph node ranges + build z ----------------
__global__ __launch_bounds__(64) void pool_csr_kernel(
    const float* __restrict__ ho, const int* __restrict__ bstart,
    const float* __restrict__ fragl, const float* __restrict__ addf, float* __restrict__ z){
  const int b = blockIdx.x >> 2, q = blockIdx.x & 3;
  const int f = q * 64 + threadIdx.x;
  const int s = bstart[b], e = bstart[b + 1];
  const float* p = ho + (size_t)s * HH + f;
  float m0 = -3.0e38f, m1 = -3.0e38f;
  int n = s;
  for (; n + 1 < e; n += 2){ m0 = fmaxf(m0, p[0]); m1 = fmaxf(m1, p[HH]); p += 2 * HH; }
  if (n < e) m0 = fmaxf(m0, p[0]);
  z[(size_t)b * 272 + f] = fmaxf(m0, m1);
  if (q == 0 && threadIdx.x < 16){
    int j = threadIdx.x;
    float v = (j < 8) ? fragl[b * 8 + j] : addf[b * 8 + (j - 8)];
    z[(size_t)b * 272 + 256 + j] = v;
  }
}

// ---------------- edge kernel: 64 SORTED edges/block, 512 threads (8 waves x 32 feats) ----------------
// Pa/Pb gathered as bf16 (L2-resident), eattr pre-sorted bf16 (coalesced, K-remapped),
// m2 stream uses non-temporal stores to preserve LLC for gathers.
template<bool STREAM>
__global__ __launch_bounds__(512, 4) void edge_kernel(
    const u16* __restrict__ Pab, const u16* __restrict__ Pbb,
    const float4* __restrict__ coord,
    const int* __restrict__ srow, const int* __restrict__ scol,
    const u16* __restrict__ eattr_s,
    const u16* __restrict__ pw1, const u16* __restrict__ pw2, const u16* __restrict__ pw3,
    const float* __restrict__ b2, const float* __restrict__ cb1, const float* __restrict__ cw2,
    float* __restrict__ agg, float* __restrict__ cacc, u64* __restrict__ m2g){
  __shared__ ulonglong2 mt2[2048];    // 32KB pair tile [64 edges][32 pairs]
  __shared__ float4 dif[64];
  __shared__ int rows_s[64];
  __shared__ int cols_s[64];
  __shared__ float bias_s[768];       // b2 | cb1 | cw2
  __shared__ float cpart[8][64];

  const int tid = threadIdx.x;
  const int w = tid >> 6, l = tid & 63, g = l >> 4, li = l & 15;
  const int wg = (blockIdx.x & 7) * 625 + (blockIdx.x >> 3);
  const int eb = wg * 64;

  if (tid < 64){
    int sp = eb + tid;
    int r = srow[sp], c = scol[sp];
    rows_s[tid] = r; cols_s[tid] = c;
    float4 ca = coord[r], cb = coord[c];
    float dx = ca.x - cb.x, dy = ca.y - cb.y, dz = ca.z - cb.z;
    float rad = dx*dx + dy*dy + dz*dz;
    dif[tid] = make_float4(dx, dy, dz, rad);
  }
  for (int i = tid; i < 768; i += 512){
    float v;
    if      (i < 256) v = b2[i];
    else if (i < 512) v = cb1[i - 256];
    else              v = cw2[i - 512];
    bias_s[i] = v;
  }
  __syncthreads();

  const u16* paP[4]; const u16* pbP[4];
  int pbase[4], pm4[4], wrI[4];
  #pragma unroll
  for (int nf = 0; nf < 4; ++nf){
    int e = nf * 16 + li;
    paP[nf] = Pab + (size_t)rows_s[e] * HH;
    pbP[nf] = Pbb + (size_t)cols_s[e] * HH;
    pbase[nf] = e * 32 + (g ^ (e & 3));
    pm4[nf] = e & 4;
    wrI[nf] = pbase[nf] + ((4 * w) ^ pm4[nf]);
  }

  // ---- EARLY Pa/Pb gather issue (bf16, 8B/frag; latency hides under tail MFMA)
  u64 pa[2][4], pb[2][4];
  #pragma unroll
  for (int mf = 0; mf < 2; ++mf){
    const int fb = w * 32 + mf * 16 + g * 4;
    #pragma unroll
    for (int nf = 0; nf < 4; ++nf){
      pa[mf][nf] = *(const u64*)(paP[nf] + fb);
      pb[mf][nf] = *(const u64*)(pbP[nf] + fb);
    }
  }

  const u16* pw1b = pw1 + ((size_t)(w * 2) * 64 + l) * 8;
  const u16* pw2b = pw2 + ((size_t)(w * 2) * 64 + l) * 8;
  const u16* pw3b = pw3 + ((size_t)(w * 2) * 64 + l) * 8;

  f4v acc[2][4];
  #pragma unroll
  for (int a = 0; a < 2; ++a)
    #pragma unroll
    for (int b = 0; b < 4; ++b) acc[a][b] = (f4v){0.f,0.f,0.f,0.f};

  // ---- tail MFMA: k 512..527 = eattr_s (aligned 8B), k 528 = radial (hi half, g==0)
  {
    s8v at[2];
    #pragma unroll
    for (int mf = 0; mf < 2; ++mf) at[mf] = *(const s8v*)(pw1b + (size_t)16 * 8192 + mf * 512);
    #pragma unroll
    for (int nf = 0; nf < 4; ++nf){
      int e = nf * 16 + li;
      BU bu;
      bu.d[0] = *(const u64*)(eattr_s + (size_t)(eb + e) * 16 + g * 4);
      bu.d[1] = (g == 0) ? (u64)f2bf(dif[e].w) : 0;
      #pragma unroll
      for (int mf = 0; mf < 2; ++mf)
        acc[mf][nf] = __builtin_amdgcn_mfma_f32_16x16x32_bf16(at[mf], bu.v, acc[mf][nf], 0, 0, 0);
    }
  }

  // ---- m1 = silu(acc + Pa[row] + Pb[col])  (b1 folded into Pa) -> b128 tile write
  #pragma unroll
  for (int nf = 0; nf < 4; ++nf){
    ulonglong2 t;
    #pragma unroll
    for (int mf = 0; mf < 2; ++mf){
      float4 fa = up4(pa[mf][nf]);
      float4 fbv = up4(pb[mf][nf]);
      float v0 = siluf(acc[mf][nf][0] + fa.x + fbv.x);
      float v1 = siluf(acc[mf][nf][1] + fa.y + fbv.y);
      float v2 = siluf(acc[mf][nf][2] + fa.z + fbv.z);
      float v3 = siluf(acc[mf][nf][3] + fa.w + fbv.w);
      u64 p4 = pack4bf(v0, v1, v2, v3);
      if (mf == 0) t.x = p4; else t.y = p4;
    }
    mt2[wrI[nf]] = t;
  }
  __syncthreads();

  // ---- GEMM2: m2 = silu(m1 @ W2 + b2)
  #pragma unroll
  for (int a = 0; a < 2; ++a)
    #pragma unroll
    for (int b = 0; b < 4; ++b) acc[a][b] = (f4v){0.f,0.f,0.f,0.f};
  #pragma unroll
  for (int s = 0; s < 8; ++s){
    s8v A[2];
    #pragma unroll
    for (int mf = 0; mf < 2; ++mf) A[mf] = *(const s8v*)(pw2b + (size_t)s * 8192 + mf * 512);
    #pragma unroll
    for (int nf = 0; nf < 4; ++nf){
      ulonglong2 pr = mt2[pbase[nf] + ((4 * s) ^ pm4[nf])];
      BU bu; bu.d[0] = pr.x; bu.d[1] = pr.y;
      #pragma unroll
      for (int mf = 0; mf < 2; ++mf)
        acc[mf][nf] = __builtin_amdgcn_mfma_f32_16x16x32_bf16(A[mf], bu.v, acc[mf][nf], 0, 0, 0);
    }
  }
  u64 pm2[2][4];
  #pragma unroll
  for (int mf = 0; mf < 2; ++mf){
    const int fb = w * 32 + mf * 16 + g * 4;
    const float4 bb = *(const float4*)&bias_s[fb];
    #pragma unroll
    for (int nf = 0; nf < 4; ++nf)
      pm2[mf][nf] = pack4bf(siluf(acc[mf][nf][0] + bb.x),
                            siluf(acc[mf][nf][1] + bb.y),
                            siluf(acc[mf][nf][2] + bb.z),
                            siluf(acc[mf][nf][3] + bb.w));
  }
  __syncthreads();                    // all waves done reading m1
  #pragma unroll
  for (int nf = 0; nf < 4; ++nf){
    ulonglong2 t; t.x = pm2[0][nf]; t.y = pm2[1][nf];
    mt2[wrI[nf]] = t;
  }
  __syncthreads();

  // ---- STREAM: coalesced NON-TEMPORAL write-out of m2 (don't thrash LLC)
  if (STREAM){
    const u64* mtU = (const u64*)mt2;
    u64* dst = m2g + (size_t)eb * 64;
    #pragma unroll
    for (int j = 0; j < 8; ++j){
      int q8 = j * 512 + tid;
      int e = q8 >> 6, c = q8 & 63;
      int q = (c & 0x38) | ((c & 3) << 1) | ((c >> 2) & 1);
      __builtin_nontemporal_store(mtU[(e << 6) + (q ^ ((e & 7) << 1))], &dst[q8]);
    }
  }

  // ---- GEMM3: q = silu(m2 @ CW1 + cb1); c = q . cw2
  #pragma unroll
  for (int a = 0; a < 2; ++a)
    #pragma unroll
    for (int b = 0; b < 4; ++b) acc[a][b] = (f4v){0.f,0.f,0.f,0.f};
  #pragma unroll
  for (int s = 0; s < 8; ++s){
    s8v A[2];
    #pragma unroll
    for (int mf = 0; mf < 2; ++mf) A[mf] = *(const s8v*)(pw3b + (size_t)s * 8192 + mf * 512);
    #pragma unroll
    for (int nf = 0; nf < 4; ++nf){
      ulonglong2 pr = mt2[pbase[nf] + ((4 * s) ^ pm4[nf])];
      BU bu; bu.d[0] = pr.x; bu.d[1] = pr.y;
      #pragma unroll
      for (int mf = 0; mf < 2; ++mf)
        acc[mf][nf] = __builtin_amdgcn_mfma_f32_16x16x32_bf16(A[mf], bu.v, acc[mf][nf], 0, 0, 0);
    }
  }
  float cp4[4] = {0.f, 0.f, 0.f, 0.f};
  #pragma unroll
  for (int mf = 0; mf < 2; ++mf){
    const int fb = w * 32 + mf * 16 + g * 4;
    const float4 cb = *(const float4*)&bias_s[256 + fb];
    const float4 cw = *(const float4*)&bias_s[512 + fb];
    #pragma unroll
    for (int nf = 0; nf < 4; ++nf){
      cp4[nf] += siluf(acc[mf][nf][0] + cb.x) * cw.x;
      cp4[nf] += siluf(acc[mf][nf][1] + cb.y) * cw.y;
      cp4[nf] += siluf(acc[mf][nf][2] + cb.z) * cw.z;
      cp4[nf] += siluf(acc[mf][nf][3] + cb.w) * cw.w;
    }
  }
  #pragma unroll
  for (int nf = 0; nf < 4; ++nf){
    float v = cp4[nf];
    v += __shfl_xor(v, 16, 64);
    v += __shfl_xor(v, 32, 64);
    if (g == 0) cpart[w][nf * 16 + li] = v;
  }
  __syncthreads();

  // ---- cacc: segmented suffix-reduce across the 64 sorted edges, head lanes atomic
  if (tid < 64){
    float c = cpart[0][tid] + cpart[1][tid] + cpart[2][tid] + cpart[3][tid]
            + cpart[4][tid] + cpart[5][tid] + cpart[6][tid] + cpart[7][tid];
    float4 d = dif[tid];
    const int myrow = rows_s[tid];
    float vx = d.x * c, vy = d.y * c, vz = d.z * c;
    #pragma unroll
    for (int dd = 1; dd < 64; dd <<= 1){
      const int rr = __shfl_down(myrow, dd, 64);
      const bool ok = ((tid + dd) < 64) && (rr == myrow);
      float tx = __shfl_down(vx, dd, 64);
      float ty = __shfl_down(vy, dd, 64);
      float tz = __shfl_down(vz, dd, 64);
      if (ok){ vx += tx; vy += ty; vz += tz; }
    }
    if (tid == 0 || rows_s[tid - 1] != myrow){
      atomicAdd(cacc + (size_t)myrow * 4 + 0, vx);
      atomicAdd(cacc + (size_t)myrow * 4 + 1, vy);
      atomicAdd(cacc + (size_t)myrow * 4 + 2, vz);
    }
  }

  // ---- fallback path only: agg via segmented suffix-reduce + atomics
  if (!STREAM){
    #pragma unroll
    for (int nf = 0; nf < 4; ++nf){
      const int myrow = rows_s[nf * 16 + li];
      const bool head = (li == 0) || (rows_s[nf * 16 + li - 1] != myrow);
      float v[8];
      #pragma unroll
      for (int mf = 0; mf < 2; ++mf)
        #pragma unroll
        for (int r = 0; r < 4; ++r) v[mf * 4 + r] = bf2f((u16)(pm2[mf][nf] >> (16 * r)));
      #pragma unroll
      for (int d = 1; d < 16; d <<= 1){
        const int rr = __shfl_down(myrow, d, 16);
        const bool ok = ((li + d) < 16) && (rr == myrow);
        #pragma unroll
        for (int j = 0; j < 8; ++j){
          const float vv = __shfl_down(v[j], d, 16);
          if (ok) v[j] += vv;
        }
      }
      if (head){
        #pragma unroll
        for (int mf = 0; mf < 2; ++mf){
          float* ag = agg + (size_t)myrow * HH + w * 32 + mf * 16 + g * 4;
          atomicAdd(ag + 0, v[mf * 4 + 0]);
          atomicAdd(ag + 1, v[mf * 4 + 1]);
          atomicAdd(ag + 2, v[mf * 4 + 2]);
          atomicAdd(ag + 3, v[mf * 4 + 3]);
        }
      }
    }
  }
}

// ---------------- node kernel (+ fused next-layer pab): h += MLP([h, agg]) ----------------
template<bool EMIT_PAB>
__global__ __launch_bounds__(256) void node_pab_kernel(
    float* __restrict__ h, u16* __restrict__ hb, const u16* __restrict__ agg_bf,
    const u16* __restrict__ pw1, const u16* __restrict__ pw2,
    const float* __restrict__ b1, const float* __restrict__ b2,
    const u16* __restrict__ pw1n, const float* __restrict__ b1n,
    u16* __restrict__ Pab, u16* __restrict__ Pbb){
  __shared__ ulonglong2 mt2[2048];
  __shared__ float bias_s[512];
  const int tid = threadIdx.x;
  const int w = tid >> 6, l = tid & 63, g = l >> 4, li = l & 15;
  const int nb = blockIdx.x * 64;
  for (int i = tid; i < 512; i += 256) bias_s[i] = (i < 256) ? b1[i] : b2[i - 256];
  __syncthreads();

  const u16* hp[4]; const u16* ap[4];
  int pbase[4], pm4[4];
  #pragma unroll
  for (int nf = 0; nf < 4; ++nf){
    int n = nb + nf * 16 + li; if (n >= NN) n = NN - 1;
    hp[nf] = hb     + (size_t)n * HH + g * 4;
    ap[nf] = agg_bf + (size_t)n * HH + g * 4;
    int e = nf * 16 + li;
    pbase[nf] = e * 32 + (g ^ (e & 3));
    pm4[nf] = e & 4;
  }
  f4v acc[4][4];
  #pragma unroll
  for (int a = 0; a < 4; ++a)
    #pragma unroll
    for (int b = 0; b < 4; ++b) acc[a][b] = (f4v){0.f,0.f,0.f,0.f};

  const u16* pw1b = pw1 + ((size_t)(w * 4) * 64 + l) * 8;
  #pragma unroll 4
  for (int kb = 0; kb < 8; ++kb){
    s8v A[4];
    #pragma unroll
    for (int mf = 0; mf < 4; ++mf) A[mf] = *(const s8v*)(pw1b + (size_t)kb * 8192 + mf * 512);
    #pragma unroll
    for (int nf = 0; nf < 4; ++nf){
      BU bu;
      bu.d[0] = *(const u64*)(hp[nf] + kb * 32);
      bu.d[1] = *(const u64*)(hp[nf] + kb * 32 + 16);
      #pragma unroll
      for (int mf = 0; mf < 4; ++mf)
        acc[mf][nf] = __builtin_amdgcn_mfma_f32_16x16x32_bf16(A[mf], bu.v, acc[mf][nf], 0, 0, 0);
    }
  }
  #pragma unroll 4
  for (int kb = 8; kb < 16; ++kb){
    s8v A[4];
    #pragma unroll
    for (int mf = 0; mf < 4; ++mf) A[mf] = *(const s8v*)(pw1b + (size_t)kb * 8192 + mf * 512);
    #pragma unroll
    for (int nf = 0; nf < 4; ++nf){
      BU bu;
      bu.d[0] = *(const u64*)(ap[nf] + (kb - 8) * 32);
      bu.d[1] = *(const u64*)(ap[nf] + (kb - 8) * 32 + 16);
      #pragma unroll
      for (int mf = 0; mf < 4; ++mf)
        acc[mf][nf] = __builtin_amdgcn_mfma_f32_16x16x32_bf16(A[mf], bu.v, acc[mf][nf], 0, 0, 0);
    }
  }
  #pragma unroll
  for (int nf = 0; nf < 4; ++nf){
    u64 p01[4];
    #pragma unroll
    for (int mf = 0; mf < 4; ++mf){
      const int fb = w * 64 + mf * 16 + g * 4;
      const float4 bb = *(const float4*)&bias_s[fb];
      p01[mf] = pack4bf(siluf(acc[mf][nf][0] + bb.x), siluf(acc[mf][nf][1] + bb.y),
                        siluf(acc[mf][nf][2] + bb.z), siluf(acc[mf][nf][3] + bb.w));
    }
    ulonglong2 t0; t0.x = p01[0]; t0.y = p01[1];
    ulonglong2 t1; t1.x = p01[2]; t1.y = p01[3];
    mt2[pbase[nf] + ((8 * w)     ^ pm4[nf])] = t0;
    mt2[pbase[nf] + ((8 * w + 4) ^ pm4[nf])] = t1;
  }
  __syncthreads();

  #pragma unroll
  for (int a = 0; a < 4; ++a)
    #pragma unroll
    for (int b = 0; b < 4; ++b) acc[a][b] = (f4v){0.f,0.f,0.f,0.f};
  const u16* pw2b = pw2 + ((size_t)(w * 4) * 64 + l) * 8;
  #pragma unroll 4
  for (int kb = 0; kb < 8; ++kb){
    s8v A[4];
    #pragma unroll
    for (int mf = 0; mf < 4; ++mf) A[mf] = *(const s8v*)(pw2b + (size_t)kb * 8192 + mf * 512);
    #pragma unroll
    for (int nf = 0; nf < 4; ++nf){
      ulonglong2 pr = mt2[pbase[nf] + ((4 * kb) ^ pm4[nf])];
      BU bu; bu.d[0] = pr.x; bu.d[1] = pr.y;
      #pragma unroll
      for (int mf = 0; mf < 4; ++mf)
        acc[mf][nf] = __builtin_amdgcn_mfma_f32_16x16x32_bf16(A[mf], bu.v, acc[mf][nf], 0, 0, 0);
    }
  }
  __syncthreads();                    // done reading n1 tile
  u64 pm[4][4];
  #pragma unroll
  for (int mf = 0; mf < 4; ++mf){
    const int fb = w * 64 + mf * 16 + g * 4;
    const float4 bb = *(const float4*)&bias_s[256 + fb];
    #pragma unroll
    for (int nf = 0; nf < 4; ++nf){
      int n = nb + nf * 16 + li;
      int nc = (n >= NN) ? NN - 1 : n;
      float4 hv = *(float4*)(h + (size_t)nc * HH + fb);
      float o0 = hv.x + acc[mf][nf][0] + bb.x;
      float o1 = hv.y + acc[mf][nf][1] + bb.y;
      float o2 = hv.z + acc[mf][nf][2] + bb.z;
      float o3 = hv.w + acc[mf][nf][3] + bb.w;
      pm[mf][nf] = pack4bf(o0, o1, o2, o3);
      if (n < NN){
        *(float4*)(h + (size_t)n * HH + fb) = make_float4(o0, o1, o2, o3);
        *(u64*)(hb + (size_t)n * HH + fb) = pm[mf][nf];
      }
    }
  }
  if (EMIT_PAB){
    #pragma unroll
    for (int nf = 0; nf < 4; ++nf){
      ulonglong2 t0; t0.x = pm[0][nf]; t0.y = pm[1][nf];
      ulonglong2 t1; t1.x = pm[2][nf]; t1.y = pm[3][nf];
      mt2[pbase[nf] + ((8 * w)     ^ pm4[nf])] = t0;
      mt2[pbase[nf] + ((8 * w + 4) ^ pm4[nf])] = t1;
    }
    __syncthreads();
    const u16* pwn = pw1n + ((size_t)(w * 4) * 64 + l) * 8;
    #pragma unroll
    for (int pass = 0; pass < 2; ++pass){
      #pragma unroll
      for (int a = 0; a < 4; ++a)
        #pragma unroll
        for (int b = 0; b < 4; ++b) acc[a][b] = (f4v){0.f,0.f,0.f,0.f};
      const u16* pwp = pwn + (size_t)(pass * 8) * 8192;
      #pragma unroll 4
      for (int kb = 0; kb < 8; ++kb){
        s8v A[4];
        #pragma unroll
        for (int mf = 0; mf < 4; ++mf) A[mf] = *(const s8v*)(pwp + (size_t)kb * 8192 + mf * 512);
        #pragma unroll
        for (int nf = 0; nf < 4; ++nf){
          ulonglong2 pr = mt2[pbase[nf] + ((4 * kb) ^ pm4[nf])];
          BU bu; bu.d[0] = pr.x; bu.d[1] = pr.y;
          #pragma unroll
          for (int mf = 0; mf < 4; ++mf)
            acc[mf][nf] = __builtin_amdgcn_mfma_f32_16x16x32_bf16(A[mf], bu.v, acc[mf][nf], 0, 0, 0);
        }
      }
      u16* dst = pass ? Pbb : Pab;
      #pragma unroll
      for (int mf = 0; mf < 4; ++mf){
        const int fb = w * 64 + mf * 16 + g * 4;
        float c0 = 0.f, c1 = 0.f, c2 = 0.f, c3 = 0.f;
        if (!pass){ c0 = b1n[fb]; c1 = b1n[fb+1]; c2 = b1n[fb+2]; c3 = b1n[fb+3]; }
        #pragma unroll
        for (int nf = 0; nf < 4; ++nf){
          int n = nb + nf * 16 + li;
          if (n < NN)
            *(u64*)(dst + (size_t)n * HH + fb) =
              pack4bf(acc[mf][nf][0] + c0, acc[mf][nf][1] + c1,
                      acc[mf][nf][2] + c2, acc[mf][nf][3] + c3);
        }
      }
    }
  }
}

// ---------------- resblock + head ----------------
__global__ __launch_bounds__(256) void final_kernel(
    const float* __restrict__ z, const float* __restrict__ rw1, const float* __restrict__ rb1,
    const float* __restrict__ rw2, const float* __restrict__ rb2,
    const float* __restrict__ hw, const float* __restrict__ hbs, float* __restrict__ out){
  __shared__ float zr[272], t1[256], t2[272];
  const int b = blockIdx.x, tid = threadIdx.x;
  for (int i = tid; i < 272; i += 256) zr[i] = z[(size_t)b * 272 + i];
  __syncthreads();
  {
    float a = rb1[tid];
    for (int k = 0; k < 272; ++k) a += zr[k] * rw1[(size_t)k * 256 + tid];
    t1[tid] = siluf(a);
  }
  __syncthreads();
  for (int i = tid; i < 272; i += 256){
    float a = rb2[i] + zr[i];
    for (int k = 0; k < 256; ++k) a += t1[k] * rw2[(size_t)k * 272 + i];
    t2[i] = a;
  }
  __syncthreads();
  for (int p = tid; p < 2000; p += 256){
    float a = hbs[p];
    for (int k = 0; k < 272; ++k) a += t2[k] * hw[(size_t)k * 2000 + p];
    out[(size_t)b * 2000 + p] = a;
  }
}

extern "C" void kernel_launch(void* const* d_in, const int* in_sizes, int n_in,
                              void* d_out, int out_size, void* d_ws, size_t ws_size,
                              hipStream_t stream){
  const float* x        = (const float*)d_in[0];
  const float* pos      = (const float*)d_in[1];
  const float* eattr    = (const float*)d_in[2];
  const float* fragl    = (const float*)d_in[3];
  const float* addf     = (const float*)d_in[4];
  const int*   ei       = (const int*)d_in[5];
  const int*   batch    = (const int*)d_in[6];
  const float* emb_in_w = (const float*)d_in[7];
  const float* emb_in_b = (const float*)d_in[8];
  const float* edge_w1  = (const float*)d_in[9];
  const float* edge_b1  = (const float*)d_in[10];
  const float* edge_w2  = (const float*)d_in[11];
  const float* edge_b2  = (const float*)d_in[12];
  const float* node_w1  = (const float*)d_in[13];
  const float* node_b1  = (const float*)d_in[14];
  const float* node_w2  = (const float*)d_in[15];
  const float* node_b2  = (const float*)d_in[16];
  const float* coord_w1 = (const float*)d_in[17];
  const float* coord_b1 = (const float*)d_in[18];
  const float* coord_w2 = (const float*)d_in[19];
  const float* emb_out_w= (const float*)d_in[20];
  const float* emb_out_b= (const float*)d_in[21];
  const float* res_w1   = (const float*)d_in[22];
  const float* res_b1   = (const float*)d_in[23];
  const float* res_w2   = (const float*)d_in[24];
  const float* res_b2   = (const float*)d_in[25];
  const float* head_w   = (const float*)d_in[26];
  const float* head_b   = (const float*)d_in[27];

  char* ws = (char*)d_ws;
  size_t off = 0;
  auto alloc = [&](size_t bytes) -> void* {
    void* p = ws + off;
    off += (bytes + 255) & ~(size_t)255;
    return p;
  };
  float*  h      = (float*)alloc((size_t)NN * HH * 4);
  float*  agg    = (float*)alloc((size_t)NN * HH * 4);
  u16*    agg_bf = (u16*)  alloc((size_t)NN * HH * 2);
  u16*    hb     = (u16*)  alloc((size_t)NN * HH * 2);
  u16*    Pab    = (u16*)  alloc((size_t)NN * HH * 2);
  u16*    Pbb    = (u16*)  alloc((size_t)NN * HH * 2);
  float*  ho     = (float*)alloc((size_t)NN * HH * 4);
  float4* coordb = (float4*)alloc((size_t)NN * 16);
  float*  cacc   = (float*)alloc((size_t)NN * 16);
  float*  z      = (float*)alloc((size_t)BB * 272 * 4);
  u16*    packed = (u16*)  alloc((size_t)7680 * 256 * 2);
  u16*    ea_s   = (u16*)  alloc((size_t)EE * 16 * 2);
  int*    icnt   = (int*)  alloc((size_t)NN * 4);
  int*    iscan  = (int*)  alloc((size_t)NN * 4);
  int*    rstart = (int*)  alloc((size_t)NN * 4);
  int*    cursor = (int*)  alloc((size_t)NN * 4);
  int*    bsum   = (int*)  alloc((size_t)128 * 4);
  int*    bstart = (int*)  alloc((size_t)(BB + 1) * 4);
  int*    seid   = (int*)  alloc((size_t)EE * 4);
  int*    srow   = (int*)  alloc((size_t)EE * 4);
  int*    scol   = (int*)  alloc((size_t)EE * 4);
  const size_t base_off = off;
  u64*    m2g    = (u64*)  alloc((size_t)EE * HH * 2);   // 164 MB m2 stream buffer
  const bool use_stream = (off <= ws_size);
  if (base_off > ws_size) return;

  u16* pk_embin  = packed;
  u16* pk_embout = packed + 32768 + (size_t)4 * 466944;
  auto pk_ew1 = [&](int l){ return packed + 32768 + (size_t)l * 466944; };
  auto pk_ew2 = [&](int l){ return pk_ew1(l) + 139264; };
  auto pk_cw1 = [&](int l){ return pk_ew1(l) + 204800; };
  auto pk_nw1 = [&](int l){ return pk_ew1(l) + 270336; };
  auto pk_nw2 = [&](int l){ return pk_ew1(l) + 401408; };

  pack_kernel<<<16, 256, 0, stream>>>(emb_in_w, pk_embin, 128, 4, 0);
  for (int l = 0; l < 4; ++l){
    pack_kernel<<<68, 256, 0, stream>>>(edge_w1 + (size_t)l * 529 * 256, pk_ew1(l), 529, 17, 1);
    pack_kernel<<<32, 256, 0, stream>>>(edge_w2 + (size_t)l * 65536,     pk_ew2(l), 256, 8, 0);
    pack_kernel<<<32, 256, 0, stream>>>(coord_w1 + (size_t)l * 65536,    pk_cw1(l), 256, 8, 0);
    pack_kernel<<<64, 256, 0, stream>>>(node_w1 + (size_t)l * 131072,    pk_nw1(l), 512, 16, 0);
    pack_kernel<<<32, 256, 0, stream>>>(node_w2 + (size_t)l * 65536,     pk_nw2(l), 256, 8, 0);
  }
  pack_kernel<<<32, 256, 0, stream>>>(emb_out_w, pk_embout, 256, 8, 0);

  // ---- one-time edge sort by row + sorted eattr + per-graph ranges
  const int NB = (NN + 255) / 256;   // 79
  hipMemsetAsync(icnt,   0, (size_t)NN * 4, stream);
  hipMemsetAsync(cursor, 0, (size_t)NN * 4, stream);
  icnt_kernel<<<(EE + 255) / 256, 256, 0, stream>>>(ei, icnt);
  iscan_block<<<NB, 256, 0, stream>>>(icnt, iscan, bsum);
  iscan_top<<<1, 64, 0, stream>>>(bsum, NB);
  iscan_fix<<<NB, 256, 0, stream>>>(icnt, iscan, bsum, rstart);
  scatter_kernel<<<(EE + 255) / 256, 256, 0, stream>>>(ei, rstart, cursor, seid, srow, scol);
  sort_ea_kernel<<<(EE * 16 + 255) / 256, 256, 0, stream>>>(eattr, seid, ea_s);
  bstart_kernel<<<NB, 256, 0, stream>>>(batch, bstart);

  coord_init_kernel<<<79, 256, 0, stream>>>(pos, coordb);
  emb_in_kernel<<<313, 256, 0, stream>>>(x, pk_embin, emb_in_b, h, hb,
                                         pk_ew1(0), edge_b1, Pab, Pbb);

  for (int l = 0; l < 4; ++l){
    hipMemsetAsync(cacc, 0, (size_t)NN * 16, stream);
    if (use_stream){
      edge_kernel<true><<<5000, 512, 0, stream>>>(Pab, Pbb, coordb, srow, scol, ea_s,
          pk_ew1(l), pk_ew2(l), pk_cw1(l),
          edge_b2 + l * 256, coord_b1 + l * 256, coord_w2 + l * 256,
          agg, cacc, m2g);
      agg_csr_kernel<<<NN, 256, 0, stream>>>((const u16*)m2g, rstart, icnt, agg_bf);
    } else {
      hipMemsetAsync(agg, 0, (size_t)NN * HH * 4, stream);
      edge_kernel<false><<<5000, 512, 0, stream>>>(Pab, Pbb, coordb, srow, scol, ea_s,
          pk_ew1(l), pk_ew2(l), pk_cw1(l),
          edge_b2 + l * 256, coord_b1 + l * 256, coord_w2 + l * 256,
          agg, cacc, m2g);
      agg_conv_kernel<<<(NN * HH + 255) / 256, 256, 0, stream>>>(agg, agg_bf);
    }
    coord_upd_kernel<<<79, 256, 0, stream>>>(coordb, cacc, icnt);
    if (l < 3)
      node_pab_kernel<true><<<313, 256, 0, stream>>>(h, hb, agg_bf, pk_nw1(l), pk_nw2(l),
          node_b1 + l * 256, node_b2 + l * 256,
          pk_ew1(l + 1), edge_b1 + (l + 1) * 256, Pab, Pbb);
    else
      node_pab_kernel<false><<<313, 256, 0, stream>>>(h, hb, agg_bf, pk_nw1(l), pk_nw2(l),
          node_b1 + l * 256, node_b2 + l * 256,
          pk_ew1(0), edge_b1, Pab, Pbb);
  }

  emb_out_kernel<<<313, 256, 0, stream>>>(hb, pk_embout, emb_out_b, ho);
  pool_csr_kernel<<<BB * 4, 64, 0, stream>>>(ho, bstart, fragl, addf, z);
  final_kernel<<<128, 256, 0, stream>>>(z, res_w1, res_b1, res_w2, res_b2, head_w, head_b,
                                        (float*)d_out);
}

// Round 11
// 1434.264 us; speedup vs baseline: 1.1147x; 1.1147x over previous
//
#include <hip/hip_runtime.h>

typedef unsigned short u16;
typedef unsigned int   u32;
typedef unsigned long long u64;
typedef __attribute__((ext_vector_type(8))) short s8v;   // 8 bf16 (4 VGPRs) MFMA operand
typedef __attribute__((ext_vector_type(4))) float f4v;   // MFMA accumulator

#define NN 20000
#define EE 320000
#define BB 128
#define HH 256

union BU { u64 d[2]; s8v v; };

__device__ __forceinline__ u16 f2bf(float f){
  u32 u = __float_as_uint(f);
  return (u16)((u + 0x7FFFu + ((u >> 16) & 1u)) >> 16);   // RNE
}
__device__ __forceinline__ float bf2f(u16 u){ return __uint_as_float((u32)u << 16); }
__device__ __forceinline__ u32 cvt2(float a, float b){
  u32 r; asm("v_cvt_pk_bf16_f32 %0, %1, %2" : "=v"(r) : "v"(a), "v"(b)); return r;
}
__device__ __forceinline__ u64 pack4bf(float a, float b, float c, float d){
  return (u64)cvt2(a, b) | ((u64)cvt2(c, d) << 32);
}
__device__ __forceinline__ float4 up4(u64 v){
  return make_float4(bf2f((u16)v), bf2f((u16)(v >> 16)), bf2f((u16)(v >> 32)), bf2f((u16)(v >> 48)));
}
// silu via v_rcp (1 instr); 1-ulp rcp error << bf16 rounding
__device__ __forceinline__ float siluf(float v){
  return v * __builtin_amdgcn_rcpf(1.0f + __expf(-v));
}

// ---------------- weight packing: W [K][256] f32 -> A-fragment blob (W^T), bf16 ----------------
// remap=1 (edge_w1): new-k 512..527 <- old 513..528 (eattr), new-k 528 <- old 512 (radial)
__global__ void pack_kernel(const float* __restrict__ src, u16* __restrict__ dst, int K, int KB, int remap){
  int t = blockIdx.x * 256 + threadIdx.x;
  if (t >= KB * 1024) return;
  int lane = t & 63, mf = (t >> 6) & 15, kb = t >> 10;
  int g = lane >> 4, li = lane & 15;
  int m = mf * 16 + li;
  u16 o[8];
  #pragma unroll
  for (int j = 0; j < 8; ++j){
    int k = kb * 32 + ((j < 4) ? (g * 4 + j) : (16 + g * 4 + (j - 4)));
    int ks = k;
    if (remap){ if (k >= 512 && k < 528) ks = k + 1; else if (k == 528) ks = 512; }
    o[j] = (k < K) ? f2bf(src[(size_t)ks * 256 + m]) : (u16)0;
  }
  u16* d = dst + ((size_t)(kb * 16 + mf) * 64 + lane) * 8;
  *(u64*)(d)     = (u64)o[0] | ((u64)o[1] << 16) | ((u64)o[2] << 32) | ((u64)o[3] << 48);
  *(u64*)(d + 4) = (u64)o[4] | ((u64)o[5] << 16) | ((u64)o[6] << 32) | ((u64)o[7] << 48);
}

// ---------------- edge sort by destination row (one-time per launch) ----------------
__global__ void icnt_kernel(const int* __restrict__ ei, int* __restrict__ icnt){
  int t = blockIdx.x * 256 + threadIdx.x;
  if (t < EE) atomicAdd(&icnt[ei[t]], 1);
}
__global__ void iscan_block(const int* __restrict__ icnt, int* __restrict__ iscan, int* __restrict__ bsum){
  __shared__ int s[256];
  int i = blockIdx.x * 256 + threadIdx.x;
  int v = (i < NN) ? icnt[i] : 0;
  s[threadIdx.x] = v; __syncthreads();
  #pragma unroll
  for (int d = 1; d < 256; d <<= 1){
    int t = (threadIdx.x >= d) ? s[threadIdx.x - d] : 0;
    __syncthreads();
    s[threadIdx.x] += t;
    __syncthreads();
  }
  if (i < NN) iscan[i] = s[threadIdx.x];
  if (threadIdx.x == 255) bsum[blockIdx.x] = s[255];
}
__global__ void iscan_top(int* __restrict__ bsum, int nb){
  if (blockIdx.x == 0 && threadIdx.x == 0){
    int acc = 0;
    for (int i = 0; i < nb; ++i){ int t = bsum[i]; bsum[i] = acc; acc += t; }
  }
}
__global__ void iscan_fix(const int* __restrict__ icnt, const int* __restrict__ iscan,
                          const int* __restrict__ bsum, int* __restrict__ rstart){
  int i = blockIdx.x * 256 + threadIdx.x;
  if (i < NN) rstart[i] = bsum[blockIdx.x] + iscan[i] - icnt[i];
}
__global__ void scatter_kernel(const int* __restrict__ ei, const int* __restrict__ rstart,
                               int* __restrict__ cursor, int* __restrict__ seid,
                               int* __restrict__ srow, int* __restrict__ scol){
  int e = blockIdx.x * 256 + threadIdx.x;
  if (e < EE){
    int r = ei[e];
    int p = rstart[r] + atomicAdd(&cursor[r], 1);
    seid[p] = e; srow[p] = r; scol[p] = ei[EE + e];
  }
}
// eattr gathered into sorted order, bf16 (one-time)
__global__ void sort_ea_kernel(const float* __restrict__ eattr, const int* __restrict__ seid,
                               u16* __restrict__ es){
  int t = blockIdx.x * 256 + threadIdx.x;
  if (t < EE * 16){
    int p = t >> 4, j = t & 15;
    es[t] = f2bf(eattr[(size_t)seid[p] * 16 + j]);
  }
}
// per-graph node ranges from the SORTED batch array (run once)
__global__ void bstart_kernel(const int* __restrict__ batch, int* __restrict__ bstart){
  int n = blockIdx.x * 256 + threadIdx.x;
  if (n >= NN) return;
  int b = batch[n];
  if (n == 0){ for (int x = 0; x <= b; ++x) bstart[x] = 0; }
  else {
    int pb = batch[n - 1];
    for (int x = pb + 1; x <= b; ++x) bstart[x] = n;
  }
  if (n == NN - 1) bstart[BB] = NN;
}

// ---------------- small utility kernels ----------------
__global__ void coord_init_kernel(const float* __restrict__ pos, float4* __restrict__ coord){
  int t = blockIdx.x * 256 + threadIdx.x;
  if (t < NN) coord[t] = make_float4(pos[3*t], pos[3*t+1], pos[3*t+2], 0.f);
}
__global__ void coord_upd_kernel(float4* __restrict__ coord, const float* __restrict__ cacc,
                                 const int* __restrict__ icnt){
  int t = blockIdx.x * 256 + threadIdx.x;
  if (t >= NN) return;
  float k = fmaxf((float)icnt[t], 1.0f);
  float4 c = coord[t];
  c.x += cacc[4*t+0] / k; c.y += cacc[4*t+1] / k; c.z += cacc[4*t+2] / k;
  coord[t] = c;
}
__global__ void agg_conv_kernel(const float* __restrict__ agg, u16* __restrict__ agg_bf){
  int t = blockIdx.x * 256 + threadIdx.x;
  if (t < NN * HH) agg_bf[t] = f2bf(agg[t]);
}

// ---------------- emb_in (+ fused pab for layer 0) ----------------
// LDS pair layout: chunk c=(a,b4,g) stored as ulonglong2 at mt2[e*32 + ((a*4+g)^(e&7))];
// pbase = e*32 + (g^(e&3)), pm4 = e&4; index(a) = pbase + ((4a)^pm4).
__global__ __launch_bounds__(256) void emb_in_kernel(
    const float* __restrict__ x, const u16* __restrict__ pw,
    const float* __restrict__ bias, float* __restrict__ h, u16* __restrict__ hb,
    const u16* __restrict__ pw1n, const float* __restrict__ b1n,
    u16* __restrict__ Pab, u16* __restrict__ Pbb){
  __shared__ ulonglong2 mt2[2048];
  const int tid = threadIdx.x;
  const int w = tid >> 6, l = tid & 63, g = l >> 4, li = l & 15;
  const int nb = blockIdx.x * 64;
  const float* xp[4];
  int pbase[4], pm4[4];
  #pragma unroll
  for (int nf = 0; nf < 4; ++nf){
    int n = nb + nf * 16 + li; if (n >= NN) n = NN - 1;
    xp[nf] = x + (size_t)n * 128 + g * 4;
    int e = nf * 16 + li;
    pbase[nf] = e * 32 + (g ^ (e & 3));
    pm4[nf] = e & 4;
  }
  f4v acc[4][4];
  #pragma unroll
  for (int a = 0; a < 4; ++a)
    #pragma unroll
    for (int b = 0; b < 4; ++b) acc[a][b] = (f4v){0.f,0.f,0.f,0.f};
  const u16* pwb = pw + ((size_t)(w * 4) * 64 + l) * 8;
  #pragma unroll
  for (int kb = 0; kb < 4; ++kb){
    s8v A[4];
    #pragma unroll
    for (int mf = 0; mf < 4; ++mf) A[mf] = *(const s8v*)(pwb + (size_t)kb * 8192 + mf * 512);
    #pragma unroll
    for (int nf = 0; nf < 4; ++nf){
      float4 fa = *(const float4*)(xp[nf] + kb * 32);
      float4 fb = *(const float4*)(xp[nf] + kb * 32 + 16);
      BU bu;
      bu.d[0] = pack4bf(fa.x, fa.y, fa.z, fa.w);
      bu.d[1] = pack4bf(fb.x, fb.y, fb.z, fb.w);
      #pragma unroll
      for (int mf = 0; mf < 4; ++mf)
        acc[mf][nf] = __builtin_amdgcn_mfma_f32_16x16x32_bf16(A[mf], bu.v, acc[mf][nf], 0, 0, 0);
    }
  }
  u64 pm[4][4];
  #pragma unroll
  for (int mf = 0; mf < 4; ++mf){
    const int fb = w * 64 + mf * 16 + g * 4;
    float b0 = bias[fb], b1 = bias[fb+1], b2 = bias[fb+2], b3 = bias[fb+3];
    #pragma unroll
    for (int nf = 0; nf < 4; ++nf){
      int n = nb + nf * 16 + li;
      float o0 = acc[mf][nf][0] + b0, o1 = acc[mf][nf][1] + b1;
      float o2 = acc[mf][nf][2] + b2, o3 = acc[mf][nf][3] + b3;
      pm[mf][nf] = pack4bf(o0, o1, o2, o3);
      if (n < NN){
        *(float4*)(h + (size_t)n * HH + fb) = make_float4(o0, o1, o2, o3);
        *(u64*)(hb + (size_t)n * HH + fb) = pm[mf][nf];
      }
    }
  }
  #pragma unroll
  for (int nf = 0; nf < 4; ++nf){
    ulonglong2 t0; t0.x = pm[0][nf]; t0.y = pm[1][nf];
    ulonglong2 t1; t1.x = pm[2][nf]; t1.y = pm[3][nf];
    mt2[pbase[nf] + ((8 * w)     ^ pm4[nf])] = t0;
    mt2[pbase[nf] + ((8 * w + 4) ^ pm4[nf])] = t1;
  }
  __syncthreads();
  const u16* pwn = pw1n + ((size_t)(w * 4) * 64 + l) * 8;
  #pragma unroll
  for (int pass = 0; pass < 2; ++pass){
    #pragma unroll
    for (int a = 0; a < 4; ++a)
      #pragma unroll
      for (int b = 0; b < 4; ++b) acc[a][b] = (f4v){0.f,0.f,0.f,0.f};
    const u16* pwp = pwn + (size_t)(pass * 8) * 8192;
    #pragma unroll 4
    for (int kb = 0; kb < 8; ++kb){
      s8v A[4];
      #pragma unroll
      for (int mf = 0; mf < 4; ++mf) A[mf] = *(const s8v*)(pwp + (size_t)kb * 8192 + mf * 512);
      #pragma unroll
      for (int nf = 0; nf < 4; ++nf){
        ulonglong2 pr = mt2[pbase[nf] + ((4 * kb) ^ pm4[nf])];
        BU bu; bu.d[0] = pr.x; bu.d[1] = pr.y;
        #pragma unroll
        for (int mf = 0; mf < 4; ++mf)
          acc[mf][nf] = __builtin_amdgcn_mfma_f32_16x16x32_bf16(A[mf], bu.v, acc[mf][nf], 0, 0, 0);
      }
    }
    u16* dst = pass ? Pbb : Pab;
    #pragma unroll
    for (int mf = 0; mf < 4; ++mf){
      const int fb = w * 64 + mf * 16 + g * 4;
      float c0 = 0.f, c1 = 0.f, c2 = 0.f, c3 = 0.f;
      if (!pass){ c0 = b1n[fb]; c1 = b1n[fb+1]; c2 = b1n[fb+2]; c3 = b1n[fb+3]; }
      #pragma unroll
      for (int nf = 0; nf < 4; ++nf){
        int n = nb + nf * 16 + li;
        if (n < NN)
          *(u64*)(dst + (size_t)n * HH + fb) =
            pack4bf(acc[mf][nf][0] + c0, acc[mf][nf][1] + c1,
                    acc[mf][nf][2] + c2, acc[mf][nf][3] + c3);
      }
    }
  }
}

// ---------------- emb_out: ho = h @ emb_out_w + b ----------------
__global__ __launch_bounds__(256) void emb_out_kernel(
    const u16* __restrict__ hb, const u16* __restrict__ pw,
    const float* __restrict__ bias, float* __restrict__ ho){
  const int tid = threadIdx.x;
  const int w = tid >> 6, l = tid & 63, g = l >> 4, li = l & 15;
  const int nb = blockIdx.x * 64;
  const u16* hp[4];
  #pragma unroll
  for (int nf = 0; nf < 4; ++nf){
    int n = nb + nf * 16 + li; if (n >= NN) n = NN - 1;
    hp[nf] = hb + (size_t)n * HH + g * 4;
  }
  f4v acc[4][4];
  #pragma unroll
  for (int a = 0; a < 4; ++a)
    #pragma unroll
    for (int b = 0; b < 4; ++b) acc[a][b] = (f4v){0.f,0.f,0.f,0.f};
  const u16* pwb = pw + ((size_t)(w * 4) * 64 + l) * 8;
  #pragma unroll 4
  for (int kb = 0; kb < 8; ++kb){
    s8v A[4];
    #pragma unroll
    for (int mf = 0; mf < 4; ++mf) A[mf] = *(const s8v*)(pwb + (size_t)kb * 8192 + mf * 512);
    #pragma unroll
    for (int nf = 0; nf < 4; ++nf){
      BU bu;
      bu.d[0] = *(const u64*)(hp[nf] + kb * 32);
      bu.d[1] = *(const u64*)(hp[nf] + kb * 32 + 16);
      #pragma unroll
      for (int mf = 0; mf < 4; ++mf)
        acc[mf][nf] = __builtin_amdgcn_mfma_f32_16x16x32_bf16(A[mf], bu.v, acc[mf][nf], 0, 0, 0);
    }
  }
  #pragma unroll
  for (int mf = 0; mf < 4; ++mf){
    const int fb = w * 64 + mf * 16 + g * 4;
    float b0 = bias[fb], b1 = bias[fb+1], b2 = bias[fb+2], b3 = bias[fb+3];
    #pragma unroll
    for (int nf = 0; nf < 4; ++nf){
      int n = nb + nf * 16 + li;
      if (n < NN)
        *(float4*)(ho + (size_t)n * HH + fb) =
          make_float4(acc[mf][nf][0] + b0, acc[mf][nf][1] + b1,
                      acc[mf][nf][2] + b2, acc[mf][nf][3] + b3);
    }
  }
}

// ---------------- max-pool over contiguous per-graph node ranges + build z ----------------
__global__ __launch_bounds__(64) void pool_csr_kernel(
    const float* __restrict__ ho, const int* __restrict__ bstart,
    const float* __restrict__ fragl, const float* __restrict__ addf, float* __restrict__ z){
  const int b = blockIdx.x >> 2, q = blockIdx.x & 3;
  const int f = q * 64 + threadIdx.x;
  const int s = bstart[b], e = bstart[b + 1];
  const float* p = ho + (size_t)s * HH + f;
  float m0 = -3.0e38f, m1 = -3.0e38f;
  int n = s;
  for (; n + 1 < e; n += 2){ m0 = fmaxf(m0, p[0]); m1 = fmaxf(m1, p[HH]); p += 2 * HH; }
  if (n < e) m0 = fmaxf(m0, p[0]);
  z[(size_t)b * 272 + f] = fmaxf(m0, m1);
  if (q == 0 && threadIdx.x < 16){
    int j = threadIdx.x;
    float v = (j < 8) ? fragl[b * 8 + j] : addf[b * 8 + (j - 8)];
    z[(size_t)b * 272 + 256 + j] = v;
  }
}

// ---------------- edge kernel: 64 SORTED edges/block, 512 threads (8 waves x 32 feats) ----------------
// In-block row aggregation: after GEMM3, the m2 LDS tile is segment-summed per feature;
// rows fully contained in the block -> plain coalesced stores, boundary rows -> atomicAdd.
// Removes the m2 global stream + the separate CSR pass entirely.
__global__ __launch_bounds__(512, 4) void edge_kernel(
    const u16* __restrict__ Pab, const u16* __restrict__ Pbb,
    const float4* __restrict__ coord,
    const int* __restrict__ srow, const int* __restrict__ scol,
    const u16* __restrict__ eattr_s,
    const u16* __restrict__ pw1, const u16* __restrict__ pw2, const u16* __restrict__ pw3,
    const float* __restrict__ b2, const float* __restrict__ cb1, const float* __restrict__ cw2,
    float* __restrict__ agg, float* __restrict__ cacc){
  __shared__ ulonglong2 mt2[2048];    // 32KB pair tile [64 edges][32 pairs]
  __shared__ float4 dif[64];
  __shared__ int rows_s[64];
  __shared__ int cols_s[64];
  __shared__ float bias_s[768];       // b2 | cb1 | cw2
  __shared__ float cpart[8][64];
  __shared__ int prevrow_s, nextrow_s;

  const int tid = threadIdx.x;
  const int w = tid >> 6, l = tid & 63, g = l >> 4, li = l & 15;
  const int wg = (blockIdx.x & 7) * 625 + (blockIdx.x >> 3);
  const int eb = wg * 64;

  if (tid < 64){
    int sp = eb + tid;
    int r = srow[sp], c = scol[sp];
    rows_s[tid] = r; cols_s[tid] = c;
    float4 ca = coord[r], cb = coord[c];
    float dx = ca.x - cb.x, dy = ca.y - cb.y, dz = ca.z - cb.z;
    float rad = dx*dx + dy*dy + dz*dz;
    dif[tid] = make_float4(dx, dy, dz, rad);
  }
  if (tid == 64) prevrow_s = (eb > 0) ? srow[eb - 1] : -1;
  if (tid == 65) nextrow_s = (eb + 64 < EE) ? srow[eb + 64] : -1;
  for (int i = tid; i < 768; i += 512){
    float v;
    if      (i < 256) v = b2[i];
    else if (i < 512) v = cb1[i - 256];
    else              v = cw2[i - 512];
    bias_s[i] = v;
  }
  __syncthreads();

  const u16* paP[4]; const u16* pbP[4];
  int pbase[4], pm4[4], wrI[4];
  #pragma unroll
  for (int nf = 0; nf < 4; ++nf){
    int e = nf * 16 + li;
    paP[nf] = Pab + (size_t)rows_s[e] * HH;
    pbP[nf] = Pbb + (size_t)cols_s[e] * HH;
    pbase[nf] = e * 32 + (g ^ (e & 3));
    pm4[nf] = e & 4;
    wrI[nf] = pbase[nf] + ((4 * w) ^ pm4[nf]);
  }

  // ---- EARLY Pa/Pb gather issue (bf16, 8B/frag; latency hides under tail MFMA)
  u64 pa[2][4], pb[2][4];
  #pragma unroll
  for (int mf = 0; mf < 2; ++mf){
    const int fb = w * 32 + mf * 16 + g * 4;
    #pragma unroll
    for (int nf = 0; nf < 4; ++nf){
      pa[mf][nf] = *(const u64*)(paP[nf] + fb);
      pb[mf][nf] = *(const u64*)(pbP[nf] + fb);
    }
  }

  const u16* pw1b = pw1 + ((size_t)(w * 2) * 64 + l) * 8;
  const u16* pw2b = pw2 + ((size_t)(w * 2) * 64 + l) * 8;
  const u16* pw3b = pw3 + ((size_t)(w * 2) * 64 + l) * 8;

  f4v acc[2][4];
  #pragma unroll
  for (int a = 0; a < 2; ++a)
    #pragma unroll
    for (int b = 0; b < 4; ++b) acc[a][b] = (f4v){0.f,0.f,0.f,0.f};

  // ---- tail MFMA: k 512..527 = eattr_s (aligned 8B), k 528 = radial (hi half, g==0)
  {
    s8v at[2];
    #pragma unroll
    for (int mf = 0; mf < 2; ++mf) at[mf] = *(const s8v*)(pw1b + (size_t)16 * 8192 + mf * 512);
    #pragma unroll
    for (int nf = 0; nf < 4; ++nf){
      int e = nf * 16 + li;
      BU bu;
      bu.d[0] = *(const u64*)(eattr_s + (size_t)(eb + e) * 16 + g * 4);
      bu.d[1] = (g == 0) ? (u64)f2bf(dif[e].w) : 0;
      #pragma unroll
      for (int mf = 0; mf < 2; ++mf)
        acc[mf][nf] = __builtin_amdgcn_mfma_f32_16x16x32_bf16(at[mf], bu.v, acc[mf][nf], 0, 0, 0);
    }
  }

  // ---- m1 = silu(acc + Pa[row] + Pb[col])  (b1 folded into Pa) -> b128 tile write
  #pragma unroll
  for (int nf = 0; nf < 4; ++nf){
    ulonglong2 t;
    #pragma unroll
    for (int mf = 0; mf < 2; ++mf){
      float4 fa = up4(pa[mf][nf]);
      float4 fbv = up4(pb[mf][nf]);
      float v0 = siluf(acc[mf][nf][0] + fa.x + fbv.x);
      float v1 = siluf(acc[mf][nf][1] + fa.y + fbv.y);
      float v2 = siluf(acc[mf][nf][2] + fa.z + fbv.z);
      float v3 = siluf(acc[mf][nf][3] + fa.w + fbv.w);
      u64 p4 = pack4bf(v0, v1, v2, v3);
      if (mf == 0) t.x = p4; else t.y = p4;
    }
    mt2[wrI[nf]] = t;
  }
  __syncthreads();

  // ---- GEMM2: m2 = silu(m1 @ W2 + b2)
  #pragma unroll
  for (int a = 0; a < 2; ++a)
    #pragma unroll
    for (int b = 0; b < 4; ++b) acc[a][b] = (f4v){0.f,0.f,0.f,0.f};
  #pragma unroll
  for (int s = 0; s < 8; ++s){
    s8v A[2];
    #pragma unroll
    for (int mf = 0; mf < 2; ++mf) A[mf] = *(const s8v*)(pw2b + (size_t)s * 8192 + mf * 512);
    #pragma unroll
    for (int nf = 0; nf < 4; ++nf){
      ulonglong2 pr = mt2[pbase[nf] + ((4 * s) ^ pm4[nf])];
      BU bu; bu.d[0] = pr.x; bu.d[1] = pr.y;
      #pragma unroll
      for (int mf = 0; mf < 2; ++mf)
        acc[mf][nf] = __builtin_amdgcn_mfma_f32_16x16x32_bf16(A[mf], bu.v, acc[mf][nf], 0, 0, 0);
    }
  }
  u64 pm2[2][4];
  #pragma unroll
  for (int mf = 0; mf < 2; ++mf){
    const int fb = w * 32 + mf * 16 + g * 4;
    const float4 bb = *(const float4*)&bias_s[fb];
    #pragma unroll
    for (int nf = 0; nf < 4; ++nf)
      pm2[mf][nf] = pack4bf(siluf(acc[mf][nf][0] + bb.x),
                            siluf(acc[mf][nf][1] + bb.y),
                            siluf(acc[mf][nf][2] + bb.z),
                            siluf(acc[mf][nf][3] + bb.w));
  }
  __syncthreads();                    // all waves done reading m1
  #pragma unroll
  for (int nf = 0; nf < 4; ++nf){
    ulonglong2 t; t.x = pm2[0][nf]; t.y = pm2[1][nf];
    mt2[wrI[nf]] = t;
  }
  __syncthreads();                    // m2 tile ready (stays valid to end of kernel)

  // ---- GEMM3: q = silu(m2 @ CW1 + cb1); c = q . cw2
  #pragma unroll
  for (int a = 0; a < 2; ++a)
    #pragma unroll
    for (int b = 0; b < 4; ++b) acc[a][b] = (f4v){0.f,0.f,0.f,0.f};
  #pragma unroll
  for (int s = 0; s < 8; ++s){
    s8v A[2];
    #pragma unroll
    for (int mf = 0; mf < 2; ++mf) A[mf] = *(const s8v*)(pw3b + (size_t)s * 8192 + mf * 512);
    #pragma unroll
    for (int nf = 0; nf < 4; ++nf){
      ulonglong2 pr = mt2[pbase[nf] + ((4 * s) ^ pm4[nf])];
      BU bu; bu.d[0] = pr.x; bu.d[1] = pr.y;
      #pragma unroll
      for (int mf = 0; mf < 2; ++mf)
        acc[mf][nf] = __builtin_amdgcn_mfma_f32_16x16x32_bf16(A[mf], bu.v, acc[mf][nf], 0, 0, 0);
    }
  }
  float cp4[4] = {0.f, 0.f, 0.f, 0.f};
  #pragma unroll
  for (int mf = 0; mf < 2; ++mf){
    const int fb = w * 32 + mf * 16 + g * 4;
    const float4 cb = *(const float4*)&bias_s[256 + fb];
    const float4 cw = *(const float4*)&bias_s[512 + fb];
    #pragma unroll
    for (int nf = 0; nf < 4; ++nf){
      cp4[nf] += siluf(acc[mf][nf][0] + cb.x) * cw.x;
      cp4[nf] += siluf(acc[mf][nf][1] + cb.y) * cw.y;
      cp4[nf] += siluf(acc[mf][nf][2] + cb.z) * cw.z;
      cp4[nf] += siluf(acc[mf][nf][3] + cb.w) * cw.w;
    }
  }
  #pragma unroll
  for (int nf = 0; nf < 4; ++nf){
    float v = cp4[nf];
    v += __shfl_xor(v, 16, 64);
    v += __shfl_xor(v, 32, 64);
    if (g == 0) cpart[w][nf * 16 + li] = v;
  }
  __syncthreads();

  // ---- cacc: segmented suffix-reduce across the 64 sorted edges, head lanes atomic
  if (tid < 64){
    float c = cpart[0][tid] + cpart[1][tid] + cpart[2][tid] + cpart[3][tid]
            + cpart[4][tid] + cpart[5][tid] + cpart[6][tid] + cpart[7][tid];
    float4 d = dif[tid];
    const int myrow = rows_s[tid];
    float vx = d.x * c, vy = d.y * c, vz = d.z * c;
    #pragma unroll
    for (int dd = 1; dd < 64; dd <<= 1){
      const int rr = __shfl_down(myrow, dd, 64);
      const bool ok = ((tid + dd) < 64) && (rr == myrow);
      float tx = __shfl_down(vx, dd, 64);
      float ty = __shfl_down(vy, dd, 64);
      float tz = __shfl_down(vz, dd, 64);
      if (ok){ vx += tx; vy += ty; vz += tz; }
    }
    if (tid == 0 || rows_s[tid - 1] != myrow){
      atomicAdd(cacc + (size_t)myrow * 4 + 0, vx);
      atomicAdd(cacc + (size_t)myrow * 4 + 1, vy);
      atomicAdd(cacc + (size_t)myrow * 4 + 2, vz);
    }
  }

  // ---- agg: in-block segment-sum of the m2 tile (threads 0..255, one feature each).
  // Interior rows -> plain coalesced stores; block-boundary rows -> atomicAdd.
  if (tid < 256){
    const int f = tid;
    const int slotbase = ((f >> 5) << 2) + ((f >> 2) & 3);  // a*4 + g
    const int off16 = (((f >> 4) & 1) << 2) + (f & 3);       // b4*4 + j
    const u16* mtu = (const u16*)mt2;
    const int prow = prevrow_s, nrow = nextrow_s;
    float s = 0.f;
    int cur = rows_s[0];
    bool first = true;
    #pragma unroll 8
    for (int e = 0; e < 64; ++e){
      int r = rows_s[e];
      if (r != cur){
        float* dst = &agg[(size_t)cur * HH + f];
        if (first && cur == prow) atomicAdd(dst, s);
        else *dst = s;
        s = 0.f; cur = r; first = false;
      }
      s += bf2f(mtu[e * 256 + ((slotbase ^ (e & 7)) << 3) + off16]);
    }
    float* dst = &agg[(size_t)cur * HH + f];
    if ((first && cur == prow) || cur == nrow) atomicAdd(dst, s);
    else *dst = s;
  }
}

// ---------------- node kernel (+ fused next-layer pab): h += MLP([h, agg]) ----------------
template<bool EMIT_PAB>
__global__ __launch_bounds__(256) void node_pab_kernel(
    float* __restrict__ h, u16* __restrict__ hb, const u16* __restrict__ agg_bf,
    const u16* __restrict__ pw1, const u16* __restrict__ pw2,
    const float* __restrict__ b1, const float* __restrict__ b2,
    const u16* __restrict__ pw1n, const float* __restrict__ b1n,
    u16* __restrict__ Pab, u16* __restrict__ Pbb){
  __shared__ ulonglong2 mt2[2048];
  __shared__ float bias_s[512];
  const int tid = threadIdx.x;
  const int w = tid >> 6, l = tid & 63, g = l >> 4, li = l & 15;
  const int nb = blockIdx.x * 64;
  for (int i = tid; i < 512; i += 256) bias_s[i] = (i < 256) ? b1[i] : b2[i - 256];
  __syncthreads();

  const u16* hp[4]; const u16* ap[4];
  int pbase[4], pm4[4];
  #pragma unroll
  for (int nf = 0; nf < 4; ++nf){
    int n = nb + nf * 16 + li; if (n >= NN) n = NN - 1;
    hp[nf] = hb     + (size_t)n * HH + g * 4;
    ap[nf] = agg_bf + (size_t)n * HH + g * 4;
    int e = nf * 16 + li;
    pbase[nf] = e * 32 + (g ^ (e & 3));
    pm4[nf] = e & 4;
  }
  f4v acc[4][4];
  #pragma unroll
  for (int a = 0; a < 4; ++a)
    #pragma unroll
    for (int b = 0; b < 4; ++b) acc[a][b] = (f4v){0.f,0.f,0.f,0.f};

  const u16* pw1b = pw1 + ((size_t)(w * 4) * 64 + l) * 8;
  #pragma unroll 4
  for (int kb = 0; kb < 8; ++kb){
    s8v A[4];
    #pragma unroll
    for (int mf = 0; mf < 4; ++mf) A[mf] = *(const s8v*)(pw1b + (size_t)kb * 8192 + mf * 512);
    #pragma unroll
    for (int nf = 0; nf < 4; ++nf){
      BU bu;
      bu.d[0] = *(const u64*)(hp[nf] + kb * 32);
      bu.d[1] = *(const u64*)(hp[nf] + kb * 32 + 16);
      #pragma unroll
      for (int mf = 0; mf < 4; ++mf)
        acc[mf][nf] = __builtin_amdgcn_mfma_f32_16x16x32_bf16(A[mf], bu.v, acc[mf][nf], 0, 0, 0);
    }
  }
  #pragma unroll 4
  for (int kb = 8; kb < 16; ++kb){
    s8v A[4];
    #pragma unroll
    for (int mf = 0; mf < 4; ++mf) A[mf] = *(const s8v*)(pw1b + (size_t)kb * 8192 + mf * 512);
    #pragma unroll
    for (int nf = 0; nf < 4; ++nf){
      BU bu;
      bu.d[0] = *(const u64*)(ap[nf] + (kb - 8) * 32);
      bu.d[1] = *(const u64*)(ap[nf] + (kb - 8) * 32 + 16);
      #pragma unroll
      for (int mf = 0; mf < 4; ++mf)
        acc[mf][nf] = __builtin_amdgcn_mfma_f32_16x16x32_bf16(A[mf], bu.v, acc[mf][nf], 0, 0, 0);
    }
  }
  #pragma unroll
  for (int nf = 0; nf < 4; ++nf){
    u64 p01[4];
    #pragma unroll
    for (int mf = 0; mf < 4; ++mf){
      const int fb = w * 64 + mf * 16 + g * 4;
      const float4 bb = *(const float4*)&bias_s[fb];
      p01[mf] = pack4bf(siluf(acc[mf][nf][0] + bb.x), siluf(acc[mf][nf][1] + bb.y),
                        siluf(acc[mf][nf][2] + bb.z), siluf(acc[mf][nf][3] + bb.w));
    }
    ulonglong2 t0; t0.x = p01[0]; t0.y = p01[1];
    ulonglong2 t1; t1.x = p01[2]; t1.y = p01[3];
    mt2[pbase[nf] + ((8 * w)     ^ pm4[nf])] = t0;
    mt2[pbase[nf] + ((8 * w + 4) ^ pm4[nf])] = t1;
  }
  __syncthreads();

  #pragma unroll
  for (int a = 0; a < 4; ++a)
    #pragma unroll
    for (int b = 0; b < 4; ++b) acc[a][b] = (f4v){0.f,0.f,0.f,0.f};
  const u16* pw2b = pw2 + ((size_t)(w * 4) * 64 + l) * 8;
  #pragma unroll 4
  for (int kb = 0; kb < 8; ++kb){
    s8v A[4];
    #pragma unroll
    for (int mf = 0; mf < 4; ++mf) A[mf] = *(const s8v*)(pw2b + (size_t)kb * 8192 + mf * 512);
    #pragma unroll
    for (int nf = 0; nf < 4; ++nf){
      ulonglong2 pr = mt2[pbase[nf] + ((4 * kb) ^ pm4[nf])];
      BU bu; bu.d[0] = pr.x; bu.d[1] = pr.y;
      #pragma unroll
      for (int mf = 0; mf < 4; ++mf)
        acc[mf][nf] = __builtin_amdgcn_mfma_f32_16x16x32_bf16(A[mf], bu.v, acc[mf][nf], 0, 0, 0);
    }
  }
  __syncthreads();                    // done reading n1 tile
  u64 pm[4][4];
  #pragma unroll
  for (int mf = 0; mf < 4; ++mf){
    const int fb = w * 64 + mf * 16 + g * 4;
    const float4 bb = *(const float4*)&bias_s[256 + fb];
    #pragma unroll
    for (int nf = 0; nf < 4; ++nf){
      int n = nb + nf * 16 + li;
      int nc = (n >= NN) ? NN - 1 : n;
      float4 hv = *(float4*)(h + (size_t)nc * HH + fb);
      float o0 = hv.x + acc[mf][nf][0] + bb.x;
      float o1 = hv.y + acc[mf][nf][1] + bb.y;
      float o2 = hv.z + acc[mf][nf][2] + bb.z;
      float o3 = hv.w + acc[mf][nf][3] + bb.w;
      pm[mf][nf] = pack4bf(o0, o1, o2, o3);
      if (n < NN){
        *(float4*)(h + (size_t)n * HH + fb) = make_float4(o0, o1, o2, o3);
        *(u64*)(hb + (size_t)n * HH + fb) = pm[mf][nf];
      }
    }
  }
  if (EMIT_PAB){
    #pragma unroll
    for (int nf = 0; nf < 4; ++nf){
      ulonglong2 t0; t0.x = pm[0][nf]; t0.y = pm[1][nf];
      ulonglong2 t1; t1.x = pm[2][nf]; t1.y = pm[3][nf];
      mt2[pbase[nf] + ((8 * w)     ^ pm4[nf])] = t0;
      mt2[pbase[nf] + ((8 * w + 4) ^ pm4[nf])] = t1;
    }
    __syncthreads();
    const u16* pwn = pw1n + ((size_t)(w * 4) * 64 + l) * 8;
    #pragma unroll
    for (int pass = 0; pass < 2; ++pass){
      #pragma unroll
      for (int a = 0; a < 4; ++a)
        #pragma unroll
        for (int b = 0; b < 4; ++b) acc[a][b] = (f4v){0.f,0.f,0.f,0.f};
      const u16* pwp = pwn + (size_t)(pass * 8) * 8192;
      #pragma unroll 4
      for (int kb = 0; kb < 8; ++kb){
        s8v A[4];
        #pragma unroll
        for (int mf = 0; mf < 4; ++mf) A[mf] = *(const s8v*)(pwp + (size_t)kb * 8192 + mf * 512);
        #pragma unroll
        for (int nf = 0; nf < 4; ++nf){
          ulonglong2 pr = mt2[pbase[nf] + ((4 * kb) ^ pm4[nf])];
          BU bu; bu.d[0] = pr.x; bu.d[1] = pr.y;
          #pragma unroll
          for (int mf = 0; mf < 4; ++mf)
            acc[mf][nf] = __builtin_amdgcn_mfma_f32_16x16x32_bf16(A[mf], bu.v, acc[mf][nf], 0, 0, 0);
        }
      }
      u16* dst = pass ? Pbb : Pab;
      #pragma unroll
      for (int mf = 0; mf < 4; ++mf){
        const int fb = w * 64 + mf * 16 + g * 4;
        float c0 = 0.f, c1 = 0.f, c2 = 0.f, c3 = 0.f;
        if (!pass){ c0 = b1n[fb]; c1 = b1n[fb+1]; c2 = b1n[fb+2]; c3 = b1n[fb+3]; }
        #pragma unroll
        for (int nf = 0; nf < 4; ++nf){
          int n = nb + nf * 16 + li;
          if (n < NN)
            *(u64*)(dst + (size_t)n * HH + fb) =
              pack4bf(acc[mf][nf][0] + c0, acc[mf][nf][1] + c1,
                      acc[mf][nf][2] + c2, acc[mf][nf][3] + c3);
        }
      }
    }
  }
}

// ---------------- resblock + head ----------------
__global__ __launch_bounds__(256) void final_kernel(
    const float* __restrict__ z, const float* __restrict__ rw1, const float* __restrict__ rb1,
    const float* __restrict__ rw2, const float* __restrict__ rb2,
    const float* __restrict__ hw, const float* __restrict__ hbs, float* __restrict__ out){
  __shared__ float zr[272], t1[256], t2[272];
  const int b = blockIdx.x, tid = threadIdx.x;
  for (int i = tid; i < 272; i += 256) zr[i] = z[(size_t)b * 272 + i];
  __syncthreads();
  {
    float a = rb1[tid];
    for (int k = 0; k < 272; ++k) a += zr[k] * rw1[(size_t)k * 256 + tid];
    t1[tid] = siluf(a);
  }
  __syncthreads();
  for (int i = tid; i < 272; i += 256){
    float a = rb2[i] + zr[i];
    for (int k = 0; k < 256; ++k) a += t1[k] * rw2[(size_t)k * 272 + i];
    t2[i] = a;
  }
  __syncthreads();
  for (int p = tid; p < 2000; p += 256){
    float a = hbs[p];
    for (int k = 0; k < 272; ++k) a += t2[k] * hw[(size_t)k * 2000 + p];
    out[(size_t)b * 2000 + p] = a;
  }
}

extern "C" void kernel_launch(void* const* d_in, const int* in_sizes, int n_in,
                              void* d_out, int out_size, void* d_ws, size_t ws_size,
                              hipStream_t stream){
  const float* x        = (const float*)d_in[0];
  const float* pos      = (const float*)d_in[1];
  const float* eattr    = (const float*)d_in[2];
  const float* fragl    = (const float*)d_in[3];
  const float* addf     = (const float*)d_in[4];
  const int*   ei       = (const int*)d_in[5];
  const int*   batch    = (const int*)d_in[6];
  const float* emb_in_w = (const float*)d_in[7];
  const float* emb_in_b = (const float*)d_in[8];
  const float* edge_w1  = (const float*)d_in[9];
  const float* edge_b1  = (const float*)d_in[10];
  const float* edge_w2  = (const float*)d_in[11];
  const float* edge_b2  = (const float*)d_in[12];
  const float* node_w1  = (const float*)d_in[13];
  const float* node_b1  = (const float*)d_in[14];
  const float* node_w2  = (const float*)d_in[15];
  const float* node_b2  = (const float*)d_in[16];
  const float* coord_w1 = (const float*)d_in[17];
  const float* coord_b1 = (const float*)d_in[18];
  const float* coord_w2 = (const float*)d_in[19];
  const float* emb_out_w= (const float*)d_in[20];
  const float* emb_out_b= (const float*)d_in[21];
  const float* res_w1   = (const float*)d_in[22];
  const float* res_b1   = (const float*)d_in[23];
  const float* res_w2   = (const float*)d_in[24];
  const float* res_b2   = (const float*)d_in[25];
  const float* head_w   = (const float*)d_in[26];
  const float* head_b   = (const float*)d_in[27];

  char* ws = (char*)d_ws;
  size_t off = 0;
  auto alloc = [&](size_t bytes) -> void* {
    void* p = ws + off;
    off += (bytes + 255) & ~(size_t)255;
    return p;
  };
  float*  h      = (float*)alloc((size_t)NN * HH * 4);
  float*  agg    = (float*)alloc((size_t)NN * HH * 4);
  u16*    agg_bf = (u16*)  alloc((size_t)NN * HH * 2);
  u16*    hb     = (u16*)  alloc((size_t)NN * HH * 2);
  u16*    Pab    = (u16*)  alloc((size_t)NN * HH * 2);
  u16*    Pbb    = (u16*)  alloc((size_t)NN * HH * 2);
  float*  ho     = (float*)alloc((size_t)NN * HH * 4);
  float4* coordb = (float4*)alloc((size_t)NN * 16);
  float*  cacc   = (float*)alloc((size_t)NN * 16);
  float*  z      = (float*)alloc((size_t)BB * 272 * 4);
  u16*    packed = (u16*)  alloc((size_t)7680 * 256 * 2);
  u16*    ea_s   = (u16*)  alloc((size_t)EE * 16 * 2);
  int*    icnt   = (int*)  alloc((size_t)NN * 4);
  int*    iscan  = (int*)  alloc((size_t)NN * 4);
  int*    rstart = (int*)  alloc((size_t)NN * 4);
  int*    cursor = (int*)  alloc((size_t)NN * 4);
  int*    bsum   = (int*)  alloc((size_t)128 * 4);
  int*    bstart = (int*)  alloc((size_t)(BB + 1) * 4);
  int*    seid   = (int*)  alloc((size_t)EE * 4);
  int*    srow   = (int*)  alloc((size_t)EE * 4);
  int*    scol   = (int*)  alloc((size_t)EE * 4);
  if (off > ws_size) return;

  u16* pk_embin  = packed;
  u16* pk_embout = packed + 32768 + (size_t)4 * 466944;
  auto pk_ew1 = [&](int l){ return packed + 32768 + (size_t)l * 466944; };
  auto pk_ew2 = [&](int l){ return pk_ew1(l) + 139264; };
  auto pk_cw1 = [&](int l){ return pk_ew1(l) + 204800; };
  auto pk_nw1 = [&](int l){ return pk_ew1(l) + 270336; };
  auto pk_nw2 = [&](int l){ return pk_ew1(l) + 401408; };

  pack_kernel<<<16, 256, 0, stream>>>(emb_in_w, pk_embin, 128, 4, 0);
  for (int l = 0; l < 4; ++l){
    pack_kernel<<<68, 256, 0, stream>>>(edge_w1 + (size_t)l * 529 * 256, pk_ew1(l), 529, 17, 1);
    pack_kernel<<<32, 256, 0, stream>>>(edge_w2 + (size_t)l * 65536,     pk_ew2(l), 256, 8, 0);
    pack_kernel<<<32, 256, 0, stream>>>(coord_w1 + (size_t)l * 65536,    pk_cw1(l), 256, 8, 0);
    pack_kernel<<<64, 256, 0, stream>>>(node_w1 + (size_t)l * 131072,    pk_nw1(l), 512, 16, 0);
    pack_kernel<<<32, 256, 0, stream>>>(node_w2 + (size_t)l * 65536,     pk_nw2(l), 256, 8, 0);
  }
  pack_kernel<<<32, 256, 0, stream>>>(emb_out_w, pk_embout, 256, 8, 0);

  // ---- one-time edge sort by row + sorted eattr + per-graph ranges
  const int NB = (NN + 255) / 256;   // 79
  hipMemsetAsync(icnt,   0, (size_t)NN * 4, stream);
  hipMemsetAsync(cursor, 0, (size_t)NN * 4, stream);
  icnt_kernel<<<(EE + 255) / 256, 256, 0, stream>>>(ei, icnt);
  iscan_block<<<NB, 256, 0, stream>>>(icnt, iscan, bsum);
  iscan_top<<<1, 64, 0, stream>>>(bsum, NB);
  iscan_fix<<<NB, 256, 0, stream>>>(icnt, iscan, bsum, rstart);
  scatter_kernel<<<(EE + 255) / 256, 256, 0, stream>>>(ei, rstart, cursor, seid, srow, scol);
  sort_ea_kernel<<<(EE * 16 + 255) / 256, 256, 0, stream>>>(eattr, seid, ea_s);
  bstart_kernel<<<NB, 256, 0, stream>>>(batch, bstart);

  coord_init_kernel<<<79, 256, 0, stream>>>(pos, coordb);
  emb_in_kernel<<<313, 256, 0, stream>>>(x, pk_embin, emb_in_b, h, hb,
                                         pk_ew1(0), edge_b1, Pab, Pbb);

  for (int l = 0; l < 4; ++l){
    hipMemsetAsync(cacc, 0, (size_t)NN * 16, stream);
    hipMemsetAsync(agg,  0, (size_t)NN * HH * 4, stream);
    edge_kernel<<<5000, 512, 0, stream>>>(Pab, Pbb, coordb, srow, scol, ea_s,
        pk_ew1(l), pk_ew2(l), pk_cw1(l),
        edge_b2 + l * 256, coord_b1 + l * 256, coord_w2 + l * 256,
        agg, cacc);
    agg_conv_kernel<<<(NN * HH + 255) / 256, 256, 0, stream>>>(agg, agg_bf);
    coord_upd_kernel<<<79, 256, 0, stream>>>(coordb, cacc, icnt);
    if (l < 3)
      node_pab_kernel<true><<<313, 256, 0, stream>>>(h, hb, agg_bf, pk_nw1(l), pk_nw2(l),
          node_b1 + l * 256, node_b2 + l * 256,
          pk_ew1(l + 1), edge_b1 + (l + 1) * 256, Pab, Pbb);
    else
      node_pab_kernel<false><<<313, 256, 0, stream>>>(h, hb, agg_bf, pk_nw1(l), pk_nw2(l),
          node_b1 + l * 256, node_b2 + l * 256,
          pk_ew1(0), edge_b1, Pab, Pbb);
  }

  emb_out_kernel<<<313, 256, 0, stream>>>(hb, pk_embout, emb_out_b, ho);
  pool_csr_kernel<<<BB * 4, 64, 0, stream>>>(ho, bstart, fragl, addf, z);
  final_kernel<<<128, 256, 0, stream>>>(z, res_w1, res_b1, res_w2, res_b2, head_w, head_b,
                                        (float*)d_out);
}

// Round 12
// 1313.425 us; speedup vs baseline: 1.2172x; 1.0920x over previous
//
#include <hip/hip_runtime.h>

typedef unsigned short u16;
typedef unsigned int   u32;
typedef unsigned long long u64;
typedef __attribute__((ext_vector_type(8))) short s8v;   // 8 bf16 (4 VGPRs) MFMA operand
typedef __attribute__((ext_vector_type(4))) float f4v;   // MFMA accumulator

#define NN 20000
#define EE 320000
#define BB 128
#define HH 256

union BU { u64 d[2]; s8v v; };

__device__ __forceinline__ u16 f2bf(float f){
  u32 u = __float_as_uint(f);
  return (u16)((u + 0x7FFFu + ((u >> 16) & 1u)) >> 16);   // RNE
}
__device__ __forceinline__ float bf2f(u16 u){ return __uint_as_float((u32)u << 16); }
__device__ __forceinline__ u32 cvt2(float a, float b){
  u32 r; asm("v_cvt_pk_bf16_f32 %0, %1, %2" : "=v"(r) : "v"(a), "v"(b)); return r;
}
__device__ __forceinline__ u64 pack4bf(float a, float b, float c, float d){
  return (u64)cvt2(a, b) | ((u64)cvt2(c, d) << 32);
}
__device__ __forceinline__ float4 up4(u64 v){
  return make_float4(bf2f((u16)v), bf2f((u16)(v >> 16)), bf2f((u16)(v >> 32)), bf2f((u16)(v >> 48)));
}
// silu via v_rcp (1 instr); 1-ulp rcp error << bf16 rounding
__device__ __forceinline__ float siluf(float v){
  return v * __builtin_amdgcn_rcpf(1.0f + __expf(-v));
}

// ---------------- weight packing: W [K][256] f32 -> A-fragment blob (W^T), bf16 ----------------
// remap=1 (edge_w1): new-k 512..527 <- old 513..528 (eattr), new-k 528 <- old 512 (radial)
__global__ void pack_kernel(const float* __restrict__ src, u16* __restrict__ dst, int K, int KB, int remap){
  int t = blockIdx.x * 256 + threadIdx.x;
  if (t >= KB * 1024) return;
  int lane = t & 63, mf = (t >> 6) & 15, kb = t >> 10;
  int g = lane >> 4, li = lane & 15;
  int m = mf * 16 + li;
  u16 o[8];
  #pragma unroll
  for (int j = 0; j < 8; ++j){
    int k = kb * 32 + ((j < 4) ? (g * 4 + j) : (16 + g * 4 + (j - 4)));
    int ks = k;
    if (remap){ if (k >= 512 && k < 528) ks = k + 1; else if (k == 528) ks = 512; }
    o[j] = (k < K) ? f2bf(src[(size_t)ks * 256 + m]) : (u16)0;
  }
  u16* d = dst + ((size_t)(kb * 16 + mf) * 64 + lane) * 8;
  *(u64*)(d)     = (u64)o[0] | ((u64)o[1] << 16) | ((u64)o[2] << 32) | ((u64)o[3] << 48);
  *(u64*)(d + 4) = (u64)o[4] | ((u64)o[5] << 16) | ((u64)o[6] << 32) | ((u64)o[7] << 48);
}

// ---------------- edge sort by destination row (one-time per launch) ----------------
__global__ void icnt_kernel(const int* __restrict__ ei, int* __restrict__ icnt){
  int t = blockIdx.x * 256 + threadIdx.x;
  if (t < EE) atomicAdd(&icnt[ei[t]], 1);
}
__global__ void iscan_block(const int* __restrict__ icnt, int* __restrict__ iscan, int* __restrict__ bsum){
  __shared__ int s[256];
  int i = blockIdx.x * 256 + threadIdx.x;
  int v = (i < NN) ? icnt[i] : 0;
  s[threadIdx.x] = v; __syncthreads();
  #pragma unroll
  for (int d = 1; d < 256; d <<= 1){
    int t = (threadIdx.x >= d) ? s[threadIdx.x - d] : 0;
    __syncthreads();
    s[threadIdx.x] += t;
    __syncthreads();
  }
  if (i < NN) iscan[i] = s[threadIdx.x];
  if (threadIdx.x == 255) bsum[blockIdx.x] = s[255];
}
__global__ void iscan_top(int* __restrict__ bsum, int nb){
  if (blockIdx.x == 0 && threadIdx.x == 0){
    int acc = 0;
    for (int i = 0; i < nb; ++i){ int t = bsum[i]; bsum[i] = acc; acc += t; }
  }
}
__global__ void iscan_fix(const int* __restrict__ icnt, const int* __restrict__ iscan,
                          const int* __restrict__ bsum, int* __restrict__ rstart){
  int i = blockIdx.x * 256 + threadIdx.x;
  if (i < NN) rstart[i] = bsum[blockIdx.x] + iscan[i] - icnt[i];
}
__global__ void scatter_kernel(const int* __restrict__ ei, const int* __restrict__ rstart,
                               int* __restrict__ cursor, int* __restrict__ seid,
                               int* __restrict__ srow, int* __restrict__ scol){
  int e = blockIdx.x * 256 + threadIdx.x;
  if (e < EE){
    int r = ei[e];
    int p = rstart[r] + atomicAdd(&cursor[r], 1);
    seid[p] = e; srow[p] = r; scol[p] = ei[EE + e];
  }
}
// eattr gathered into sorted order, bf16 (one-time)
__global__ void sort_ea_kernel(const float* __restrict__ eattr, const int* __restrict__ seid,
                               u16* __restrict__ es){
  int t = blockIdx.x * 256 + threadIdx.x;
  if (t < EE * 16){
    int p = t >> 4, j = t & 15;
    es[t] = f2bf(eattr[(size_t)seid[p] * 16 + j]);
  }
}
// per-graph node ranges from the SORTED batch array (run once)
__global__ void bstart_kernel(const int* __restrict__ batch, int* __restrict__ bstart){
  int n = blockIdx.x * 256 + threadIdx.x;
  if (n >= NN) return;
  int b = batch[n];
  if (n == 0){ for (int x = 0; x <= b; ++x) bstart[x] = 0; }
  else {
    int pb = batch[n - 1];
    for (int x = pb + 1; x <= b; ++x) bstart[x] = n;
  }
  if (n == NN - 1) bstart[BB] = NN;
}

// ---------------- small utility kernels ----------------
__global__ void coord_init_kernel(const float* __restrict__ pos, float4* __restrict__ coord){
  int t = blockIdx.x * 256 + threadIdx.x;
  if (t < NN) coord[t] = make_float4(pos[3*t], pos[3*t+1], pos[3*t+2], 0.f);
}

// ---------------- emb_in (+ fused pab for layer 0) ----------------
// LDS pair layout: chunk c=(a,b4,g) stored as ulonglong2 at mt2[e*32 + ((a*4+g)^(e&7))];
// pbase = e*32 + (g^(e&3)), pm4 = e&4; index(a) = pbase + ((4a)^pm4).
__global__ __launch_bounds__(256) void emb_in_kernel(
    const float* __restrict__ x, const u16* __restrict__ pw,
    const float* __restrict__ bias, float* __restrict__ h, u16* __restrict__ hb,
    const u16* __restrict__ pw1n, const float* __restrict__ b1n,
    u16* __restrict__ Pab, u16* __restrict__ Pbb){
  __shared__ ulonglong2 mt2[2048];
  const int tid = threadIdx.x;
  const int w = tid >> 6, l = tid & 63, g = l >> 4, li = l & 15;
  const int nb = blockIdx.x * 64;
  const float* xp[4];
  int pbase[4], pm4[4];
  #pragma unroll
  for (int nf = 0; nf < 4; ++nf){
    int n = nb + nf * 16 + li; if (n >= NN) n = NN - 1;
    xp[nf] = x + (size_t)n * 128 + g * 4;
    int e = nf * 16 + li;
    pbase[nf] = e * 32 + (g ^ (e & 3));
    pm4[nf] = e & 4;
  }
  f4v acc[4][4];
  #pragma unroll
  for (int a = 0; a < 4; ++a)
    #pragma unroll
    for (int b = 0; b < 4; ++b) acc[a][b] = (f4v){0.f,0.f,0.f,0.f};
  const u16* pwb = pw + ((size_t)(w * 4) * 64 + l) * 8;
  #pragma unroll
  for (int kb = 0; kb < 4; ++kb){
    s8v A[4];
    #pragma unroll
    for (int mf = 0; mf < 4; ++mf) A[mf] = *(const s8v*)(pwb + (size_t)kb * 8192 + mf * 512);
    #pragma unroll
    for (int nf = 0; nf < 4; ++nf){
      float4 fa = *(const float4*)(xp[nf] + kb * 32);
      float4 fb = *(const float4*)(xp[nf] + kb * 32 + 16);
      BU bu;
      bu.d[0] = pack4bf(fa.x, fa.y, fa.z, fa.w);
      bu.d[1] = pack4bf(fb.x, fb.y, fb.z, fb.w);
      #pragma unroll
      for (int mf = 0; mf < 4; ++mf)
        acc[mf][nf] = __builtin_amdgcn_mfma_f32_16x16x32_bf16(A[mf], bu.v, acc[mf][nf], 0, 0, 0);
    }
  }
  u64 pm[4][4];
  #pragma unroll
  for (int mf = 0; mf < 4; ++mf){
    const int fb = w * 64 + mf * 16 + g * 4;
    float b0 = bias[fb], b1 = bias[fb+1], b2 = bias[fb+2], b3 = bias[fb+3];
    #pragma unroll
    for (int nf = 0; nf < 4; ++nf){
      int n = nb + nf * 16 + li;
      float o0 = acc[mf][nf][0] + b0, o1 = acc[mf][nf][1] + b1;
      float o2 = acc[mf][nf][2] + b2, o3 = acc[mf][nf][3] + b3;
      pm[mf][nf] = pack4bf(o0, o1, o2, o3);
      if (n < NN){
        *(float4*)(h + (size_t)n * HH + fb) = make_float4(o0, o1, o2, o3);
        *(u64*)(hb + (size_t)n * HH + fb) = pm[mf][nf];
      }
    }
  }
  #pragma unroll
  for (int nf = 0; nf < 4; ++nf){
    ulonglong2 t0; t0.x = pm[0][nf]; t0.y = pm[1][nf];
    ulonglong2 t1; t1.x = pm[2][nf]; t1.y = pm[3][nf];
    mt2[pbase[nf] + ((8 * w)     ^ pm4[nf])] = t0;
    mt2[pbase[nf] + ((8 * w + 4) ^ pm4[nf])] = t1;
  }
  __syncthreads();
  const u16* pwn = pw1n + ((size_t)(w * 4) * 64 + l) * 8;
  #pragma unroll
  for (int pass = 0; pass < 2; ++pass){
    #pragma unroll
    for (int a = 0; a < 4; ++a)
      #pragma unroll
      for (int b = 0; b < 4; ++b) acc[a][b] = (f4v){0.f,0.f,0.f,0.f};
    const u16* pwp = pwn + (size_t)(pass * 8) * 8192;
    #pragma unroll 4
    for (int kb = 0; kb < 8; ++kb){
      s8v A[4];
      #pragma unroll
      for (int mf = 0; mf < 4; ++mf) A[mf] = *(const s8v*)(pwp + (size_t)kb * 8192 + mf * 512);
      #pragma unroll
      for (int nf = 0; nf < 4; ++nf){
        ulonglong2 pr = mt2[pbase[nf] + ((4 * kb) ^ pm4[nf])];
        BU bu; bu.d[0] = pr.x; bu.d[1] = pr.y;
        #pragma unroll
        for (int mf = 0; mf < 4; ++mf)
          acc[mf][nf] = __builtin_amdgcn_mfma_f32_16x16x32_bf16(A[mf], bu.v, acc[mf][nf], 0, 0, 0);
      }
    }
    u16* dst = pass ? Pbb : Pab;
    #pragma unroll
    for (int mf = 0; mf < 4; ++mf){
      const int fb = w * 64 + mf * 16 + g * 4;
      float c0 = 0.f, c1 = 0.f, c2 = 0.f, c3 = 0.f;
      if (!pass){ c0 = b1n[fb]; c1 = b1n[fb+1]; c2 = b1n[fb+2]; c3 = b1n[fb+3]; }
      #pragma unroll
      for (int nf = 0; nf < 4; ++nf){
        int n = nb + nf * 16 + li;
        if (n < NN)
          *(u64*)(dst + (size_t)n * HH + fb) =
            pack4bf(acc[mf][nf][0] + c0, acc[mf][nf][1] + c1,
                    acc[mf][nf][2] + c2, acc[mf][nf][3] + c3);
      }
    }
  }
}

// ---------------- emb_out: ho = h @ emb_out_w + b ----------------
__global__ __launch_bounds__(256) void emb_out_kernel(
    const u16* __restrict__ hb, const u16* __restrict__ pw,
    const float* __restrict__ bias, float* __restrict__ ho){
  const int tid = threadIdx.x;
  const int w = tid >> 6, l = tid & 63, g = l >> 4, li = l & 15;
  const int nb = blockIdx.x * 64;
  const u16* hp[4];
  #pragma unroll
  for (int nf = 0; nf < 4; ++nf){
    int n = nb + nf * 16 + li; if (n >= NN) n = NN - 1;
    hp[nf] = hb + (size_t)n * HH + g * 4;
  }
  f4v acc[4][4];
  #pragma unroll
  for (int a = 0; a < 4; ++a)
    #pragma unroll
    for (int b = 0; b < 4; ++b) acc[a][b] = (f4v){0.f,0.f,0.f,0.f};
  const u16* pwb = pw + ((size_t)(w * 4) * 64 + l) * 8;
  #pragma unroll 4
  for (int kb = 0; kb < 8; ++kb){
    s8v A[4];
    #pragma unroll
    for (int mf = 0; mf < 4; ++mf) A[mf] = *(const s8v*)(pwb + (size_t)kb * 8192 + mf * 512);
    #pragma unroll
    for (int nf = 0; nf < 4; ++nf){
      BU bu;
      bu.d[0] = *(const u64*)(hp[nf] + kb * 32);
      bu.d[1] = *(const u64*)(hp[nf] + kb * 32 + 16);
      #pragma unroll
      for (int mf = 0; mf < 4; ++mf)
        acc[mf][nf] = __builtin_amdgcn_mfma_f32_16x16x32_bf16(A[mf], bu.v, acc[mf][nf], 0, 0, 0);
    }
  }
  #pragma unroll
  for (int mf = 0; mf < 4; ++mf){
    const int fb = w * 64 + mf * 16 + g * 4;
    float b0 = bias[fb], b1 = bias[fb+1], b2 = bias[fb+2], b3 = bias[fb+3];
    #pragma unroll
    for (int nf = 0; nf < 4; ++nf){
      int n = nb + nf * 16 + li;
      if (n < NN)
        *(float4*)(ho + (size_t)n * HH + fb) =
          make_float4(acc[mf][nf][0] + b0, acc[mf][nf][1] + b1,
                      acc[mf][nf][2] + b2, acc[mf][nf][3] + b3);
    }
  }
}

// ---------------- max-pool over contiguous per-graph node ranges + build z ----------------
__global__ __launch_bounds__(64) void pool_csr_kernel(
    const float* __restrict__ ho, const int* __restrict__ bstart,
    const float* __restrict__ fragl, const float* __restrict__ addf, float* __restrict__ z){
  const int b = blockIdx.x >> 2, q = blockIdx.x & 3;
  const int f = q * 64 + threadIdx.x;
  const int s = bstart[b], e = bstart[b + 1];
  const float* p = ho + (size_t)s * HH + f;
  float m0 = -3.0e38f, m1 = -3.0e38f;
  int n = s;
  for (; n + 1 < e; n += 2){ m0 = fmaxf(m0, p[0]); m1 = fmaxf(m1, p[HH]); p += 2 * HH; }
  if (n < e) m0 = fmaxf(m0, p[0]);
  z[(size_t)b * 272 + f] = fmaxf(m0, m1);
  if (q == 0 && threadIdx.x < 16){
    int j = threadIdx.x;
    float v = (j < 8) ? fragl[b * 8 + j] : addf[b * 8 + (j - 8)];
    z[(size_t)b * 272 + 256 + j] = v;
  }
}

// ---------------- edge kernel: 64 SORTED edges/block, 512 threads (8 waves x 32 feats) ----------------
// In-block row aggregation over m2 LDS tile; agg phase split across ALL 512 threads
// (feature f x half h, 32 edges each) to halve the serial chain.
__global__ __launch_bounds__(512, 4) void edge_kernel(
    const u16* __restrict__ Pab, const u16* __restrict__ Pbb,
    const float4* __restrict__ coord,
    const int* __restrict__ srow, const int* __restrict__ scol,
    const u16* __restrict__ eattr_s,
    const u16* __restrict__ pw1, const u16* __restrict__ pw2, const u16* __restrict__ pw3,
    const float* __restrict__ b2, const float* __restrict__ cb1, const float* __restrict__ cw2,
    float* __restrict__ agg, float* __restrict__ cacc){
  __shared__ ulonglong2 mt2[2048];    // 32KB pair tile [64 edges][32 pairs]
  __shared__ float4 dif[64];
  __shared__ int rows_s[64];
  __shared__ int cols_s[64];
  __shared__ float bias_s[768];       // b2 | cb1 | cw2
  __shared__ float cpart[8][64];
  __shared__ int prevrow_s, nextrow_s;

  const int tid = threadIdx.x;
  const int w = tid >> 6, l = tid & 63, g = l >> 4, li = l & 15;
  const int wg = (blockIdx.x & 7) * 625 + (blockIdx.x >> 3);
  const int eb = wg * 64;

  if (tid < 64){
    int sp = eb + tid;
    int r = srow[sp], c = scol[sp];
    rows_s[tid] = r; cols_s[tid] = c;
    float4 ca = coord[r], cb = coord[c];
    float dx = ca.x - cb.x, dy = ca.y - cb.y, dz = ca.z - cb.z;
    float rad = dx*dx + dy*dy + dz*dz;
    dif[tid] = make_float4(dx, dy, dz, rad);
  }
  if (tid == 64) prevrow_s = (eb > 0) ? srow[eb - 1] : -1;
  if (tid == 65) nextrow_s = (eb + 64 < EE) ? srow[eb + 64] : -1;
  for (int i = tid; i < 768; i += 512){
    float v;
    if      (i < 256) v = b2[i];
    else if (i < 512) v = cb1[i - 256];
    else              v = cw2[i - 512];
    bias_s[i] = v;
  }
  __syncthreads();

  const u16* paP[4]; const u16* pbP[4];
  int pbase[4], pm4[4], wrI[4];
  #pragma unroll
  for (int nf = 0; nf < 4; ++nf){
    int e = nf * 16 + li;
    paP[nf] = Pab + (size_t)rows_s[e] * HH;
    pbP[nf] = Pbb + (size_t)cols_s[e] * HH;
    pbase[nf] = e * 32 + (g ^ (e & 3));
    pm4[nf] = e & 4;
    wrI[nf] = pbase[nf] + ((4 * w) ^ pm4[nf]);
  }

  // ---- EARLY Pa/Pb gather issue (bf16, 8B/frag; latency hides under tail MFMA)
  u64 pa[2][4], pb[2][4];
  #pragma unroll
  for (int mf = 0; mf < 2; ++mf){
    const int fb = w * 32 + mf * 16 + g * 4;
    #pragma unroll
    for (int nf = 0; nf < 4; ++nf){
      pa[mf][nf] = *(const u64*)(paP[nf] + fb);
      pb[mf][nf] = *(const u64*)(pbP[nf] + fb);
    }
  }

  const u16* pw1b = pw1 + ((size_t)(w * 2) * 64 + l) * 8;
  const u16* pw2b = pw2 + ((size_t)(w * 2) * 64 + l) * 8;
  const u16* pw3b = pw3 + ((size_t)(w * 2) * 64 + l) * 8;

  f4v acc[2][4];
  #pragma unroll
  for (int a = 0; a < 2; ++a)
    #pragma unroll
    for (int b = 0; b < 4; ++b) acc[a][b] = (f4v){0.f,0.f,0.f,0.f};

  // ---- tail MFMA: k 512..527 = eattr_s (aligned 8B), k 528 = radial (hi half, g==0)
  {
    s8v at[2];
    #pragma unroll
    for (int mf = 0; mf < 2; ++mf) at[mf] = *(const s8v*)(pw1b + (size_t)16 * 8192 + mf * 512);
    #pragma unroll
    for (int nf = 0; nf < 4; ++nf){
      int e = nf * 16 + li;
      BU bu;
      bu.d[0] = *(const u64*)(eattr_s + (size_t)(eb + e) * 16 + g * 4);
      bu.d[1] = (g == 0) ? (u64)f2bf(dif[e].w) : 0;
      #pragma unroll
      for (int mf = 0; mf < 2; ++mf)
        acc[mf][nf] = __builtin_amdgcn_mfma_f32_16x16x32_bf16(at[mf], bu.v, acc[mf][nf], 0, 0, 0);
    }
  }

  // ---- m1 = silu(acc + Pa[row] + Pb[col])  (b1 folded into Pa) -> b128 tile write
  #pragma unroll
  for (int nf = 0; nf < 4; ++nf){
    ulonglong2 t;
    #pragma unroll
    for (int mf = 0; mf < 2; ++mf){
      float4 fa = up4(pa[mf][nf]);
      float4 fbv = up4(pb[mf][nf]);
      float v0 = siluf(acc[mf][nf][0] + fa.x + fbv.x);
      float v1 = siluf(acc[mf][nf][1] + fa.y + fbv.y);
      float v2 = siluf(acc[mf][nf][2] + fa.z + fbv.z);
      float v3 = siluf(acc[mf][nf][3] + fa.w + fbv.w);
      u64 p4 = pack4bf(v0, v1, v2, v3);
      if (mf == 0) t.x = p4; else t.y = p4;
    }
    mt2[wrI[nf]] = t;
  }
  __syncthreads();

  // ---- GEMM2: m2 = silu(m1 @ W2 + b2)
  #pragma unroll
  for (int a = 0; a < 2; ++a)
    #pragma unroll
    for (int b = 0; b < 4; ++b) acc[a][b] = (f4v){0.f,0.f,0.f,0.f};
  #pragma unroll
  for (int s = 0; s < 8; ++s){
    s8v A[2];
    #pragma unroll
    for (int mf = 0; mf < 2; ++mf) A[mf] = *(const s8v*)(pw2b + (size_t)s * 8192 + mf * 512);
    #pragma unroll
    for (int nf = 0; nf < 4; ++nf){
      ulonglong2 pr = mt2[pbase[nf] + ((4 * s) ^ pm4[nf])];
      BU bu; bu.d[0] = pr.x; bu.d[1] = pr.y;
      #pragma unroll
      for (int mf = 0; mf < 2; ++mf)
        acc[mf][nf] = __builtin_amdgcn_mfma_f32_16x16x32_bf16(A[mf], bu.v, acc[mf][nf], 0, 0, 0);
    }
  }
  u64 pm2[2][4];
  #pragma unroll
  for (int mf = 0; mf < 2; ++mf){
    const int fb = w * 32 + mf * 16 + g * 4;
    const float4 bb = *(const float4*)&bias_s[fb];
    #pragma unroll
    for (int nf = 0; nf < 4; ++nf)
      pm2[mf][nf] = pack4bf(siluf(acc[mf][nf][0] + bb.x),
                            siluf(acc[mf][nf][1] + bb.y),
                            siluf(acc[mf][nf][2] + bb.z),
                            siluf(acc[mf][nf][3] + bb.w));
  }
  __syncthreads();                    // all waves done reading m1
  #pragma unroll
  for (int nf = 0; nf < 4; ++nf){
    ulonglong2 t; t.x = pm2[0][nf]; t.y = pm2[1][nf];
    mt2[wrI[nf]] = t;
  }
  __syncthreads();                    // m2 tile ready (stays valid to end of kernel)

  // ---- GEMM3: q = silu(m2 @ CW1 + cb1); c = q . cw2
  #pragma unroll
  for (int a = 0; a < 2; ++a)
    #pragma unroll
    for (int b = 0; b < 4; ++b) acc[a][b] = (f4v){0.f,0.f,0.f,0.f};
  #pragma unroll
  for (int s = 0; s < 8; ++s){
    s8v A[2];
    #pragma unroll
    for (int mf = 0; mf < 2; ++mf) A[mf] = *(const s8v*)(pw3b + (size_t)s * 8192 + mf * 512);
    #pragma unroll
    for (int nf = 0; nf < 4; ++nf){
      ulonglong2 pr = mt2[pbase[nf] + ((4 * s) ^ pm4[nf])];
      BU bu; bu.d[0] = pr.x; bu.d[1] = pr.y;
      #pragma unroll
      for (int mf = 0; mf < 2; ++mf)
        acc[mf][nf] = __builtin_amdgcn_mfma_f32_16x16x32_bf16(A[mf], bu.v, acc[mf][nf], 0, 0, 0);
    }
  }
  float cp4[4] = {0.f, 0.f, 0.f, 0.f};
  #pragma unroll
  for (int mf = 0; mf < 2; ++mf){
    const int fb = w * 32 + mf * 16 + g * 4;
    const float4 cb = *(const float4*)&bias_s[256 + fb];
    const float4 cw = *(const float4*)&bias_s[512 + fb];
    #pragma unroll
    for (int nf = 0; nf < 4; ++nf){
      cp4[nf] += siluf(acc[mf][nf][0] + cb.x) * cw.x;
      cp4[nf] += siluf(acc[mf][nf][1] + cb.y) * cw.y;
      cp4[nf] += siluf(acc[mf][nf][2] + cb.z) * cw.z;
      cp4[nf] += siluf(acc[mf][nf][3] + cb.w) * cw.w;
    }
  }
  #pragma unroll
  for (int nf = 0; nf < 4; ++nf){
    float v = cp4[nf];
    v += __shfl_xor(v, 16, 64);
    v += __shfl_xor(v, 32, 64);
    if (g == 0) cpart[w][nf * 16 + li] = v;
  }
  __syncthreads();

  // ---- cacc: segmented suffix-reduce across the 64 sorted edges, head lanes atomic
  if (tid < 64){
    float c = cpart[0][tid] + cpart[1][tid] + cpart[2][tid] + cpart[3][tid]
            + cpart[4][tid] + cpart[5][tid] + cpart[6][tid] + cpart[7][tid];
    float4 d = dif[tid];
    const int myrow = rows_s[tid];
    float vx = d.x * c, vy = d.y * c, vz = d.z * c;
    #pragma unroll
    for (int dd = 1; dd < 64; dd <<= 1){
      const int rr = __shfl_down(myrow, dd, 64);
      const bool ok = ((tid + dd) < 64) && (rr == myrow);
      float tx = __shfl_down(vx, dd, 64);
      float ty = __shfl_down(vy, dd, 64);
      float tz = __shfl_down(vz, dd, 64);
      if (ok){ vx += tx; vy += ty; vz += tz; }
    }
    if (tid == 0 || rows_s[tid - 1] != myrow){
      atomicAdd(cacc + (size_t)myrow * 4 + 0, vx);
      atomicAdd(cacc + (size_t)myrow * 4 + 1, vy);
      atomicAdd(cacc + (size_t)myrow * 4 + 2, vz);
    }
  }

  // ---- agg: in-block segment-sum of the m2 tile over ALL 512 threads:
  // thread = (feature f, half h); each half covers 32 edges. Interior runs -> store;
  // runs touching a half boundary (incl. block boundaries) -> atomicAdd.
  {
    const int f = tid & 255;
    const int half = tid >> 8;
    const int ebase = half << 5;
    const int slotbase = ((f >> 5) << 2) + ((f >> 2) & 3);  // a*4 + g
    const int off16 = (((f >> 4) & 1) << 2) + (f & 3);       // b4*4 + j
    const u16* mtu = (const u16*)mt2;
    const int prow = half ? rows_s[31] : prevrow_s;
    const int nrow = half ? nextrow_s : rows_s[32];
    float s = 0.f;
    int cur = rows_s[ebase];
    bool first = true;
    #pragma unroll 8
    for (int i = 0; i < 32; ++i){
      int e = ebase + i;
      int r = rows_s[e];
      if (r != cur){
        float* dst = &agg[(size_t)cur * HH + f];
        if (first && cur == prow) atomicAdd(dst, s);
        else *dst = s;
        s = 0.f; cur = r; first = false;
      }
      s += bf2f(mtu[e * 256 + ((slotbase ^ (e & 7)) << 3) + off16]);
    }
    float* dst = &agg[(size_t)cur * HH + f];
    if ((first && cur == prow) || cur == nrow) atomicAdd(dst, s);
    else *dst = s;
  }
}

// ---------------- node kernel (+ fused coord update + next-layer pab) ----------------
// h += MLP([h, agg]); agg consumed as f32 (conversion fused); coordb updated in preamble.
template<bool EMIT_PAB>
__global__ __launch_bounds__(256) void node_pab_kernel(
    float* __restrict__ h, u16* __restrict__ hb, const float* __restrict__ agg,
    const u16* __restrict__ pw1, const u16* __restrict__ pw2,
    const float* __restrict__ b1, const float* __restrict__ b2,
    const u16* __restrict__ pw1n, const float* __restrict__ b1n,
    u16* __restrict__ Pab, u16* __restrict__ Pbb,
    float4* __restrict__ coordb, const float* __restrict__ cacc, const int* __restrict__ icnt){
  __shared__ ulonglong2 mt2[2048];
  __shared__ float bias_s[512];
  const int tid = threadIdx.x;
  const int w = tid >> 6, l = tid & 63, g = l >> 4, li = l & 15;
  const int nb = blockIdx.x * 64;
  // fused coord update for this block's 64 nodes (cacc complete: edge kernel finished)
  if (tid < 64){
    int n = nb + tid;
    if (n < NN){
      float k = fmaxf((float)icnt[n], 1.0f);
      float4 c = coordb[n];
      c.x += cacc[4*n+0] / k; c.y += cacc[4*n+1] / k; c.z += cacc[4*n+2] / k;
      coordb[n] = c;
    }
  }
  for (int i = tid; i < 512; i += 256) bias_s[i] = (i < 256) ? b1[i] : b2[i - 256];
  __syncthreads();

  const u16* hp[4]; const float* ap[4];
  int pbase[4], pm4[4];
  #pragma unroll
  for (int nf = 0; nf < 4; ++nf){
    int n = nb + nf * 16 + li; if (n >= NN) n = NN - 1;
    hp[nf] = hb  + (size_t)n * HH + g * 4;
    ap[nf] = agg + (size_t)n * HH + g * 4;
    int e = nf * 16 + li;
    pbase[nf] = e * 32 + (g ^ (e & 3));
    pm4[nf] = e & 4;
  }
  f4v acc[4][4];
  #pragma unroll
  for (int a = 0; a < 4; ++a)
    #pragma unroll
    for (int b = 0; b < 4; ++b) acc[a][b] = (f4v){0.f,0.f,0.f,0.f};

  const u16* pw1b = pw1 + ((size_t)(w * 4) * 64 + l) * 8;
  #pragma unroll 4
  for (int kb = 0; kb < 8; ++kb){
    s8v A[4];
    #pragma unroll
    for (int mf = 0; mf < 4; ++mf) A[mf] = *(const s8v*)(pw1b + (size_t)kb * 8192 + mf * 512);
    #pragma unroll
    for (int nf = 0; nf < 4; ++nf){
      BU bu;
      bu.d[0] = *(const u64*)(hp[nf] + kb * 32);
      bu.d[1] = *(const u64*)(hp[nf] + kb * 32 + 16);
      #pragma unroll
      for (int mf = 0; mf < 4; ++mf)
        acc[mf][nf] = __builtin_amdgcn_mfma_f32_16x16x32_bf16(A[mf], bu.v, acc[mf][nf], 0, 0, 0);
    }
  }
  #pragma unroll 4
  for (int kb = 8; kb < 16; ++kb){
    s8v A[4];
    #pragma unroll
    for (int mf = 0; mf < 4; ++mf) A[mf] = *(const s8v*)(pw1b + (size_t)kb * 8192 + mf * 512);
    #pragma unroll
    for (int nf = 0; nf < 4; ++nf){
      float4 fa = *(const float4*)(ap[nf] + (kb - 8) * 32);
      float4 fb = *(const float4*)(ap[nf] + (kb - 8) * 32 + 16);
      BU bu;
      bu.d[0] = pack4bf(fa.x, fa.y, fa.z, fa.w);
      bu.d[1] = pack4bf(fb.x, fb.y, fb.z, fb.w);
      #pragma unroll
      for (int mf = 0; mf < 4; ++mf)
        acc[mf][nf] = __builtin_amdgcn_mfma_f32_16x16x32_bf16(A[mf], bu.v, acc[mf][nf], 0, 0, 0);
    }
  }
  #pragma unroll
  for (int nf = 0; nf < 4; ++nf){
    u64 p01[4];
    #pragma unroll
    for (int mf = 0; mf < 4; ++mf){
      const int fb = w * 64 + mf * 16 + g * 4;
      const float4 bb = *(const float4*)&bias_s[fb];
      p01[mf] = pack4bf(siluf(acc[mf][nf][0] + bb.x), siluf(acc[mf][nf][1] + bb.y),
                        siluf(acc[mf][nf][2] + bb.z), siluf(acc[mf][nf][3] + bb.w));
    }
    ulonglong2 t0; t0.x = p01[0]; t0.y = p01[1];
    ulonglong2 t1; t1.x = p01[2]; t1.y = p01[3];
    mt2[pbase[nf] + ((8 * w)     ^ pm4[nf])] = t0;
    mt2[pbase[nf] + ((8 * w + 4) ^ pm4[nf])] = t1;
  }
  __syncthreads();

  #pragma unroll
  for (int a = 0; a < 4; ++a)
    #pragma unroll
    for (int b = 0; b < 4; ++b) acc[a][b] = (f4v){0.f,0.f,0.f,0.f};
  const u16* pw2b = pw2 + ((size_t)(w * 4) * 64 + l) * 8;
  #pragma unroll 4
  for (int kb = 0; kb < 8; ++kb){
    s8v A[4];
    #pragma unroll
    for (int mf = 0; mf < 4; ++mf) A[mf] = *(const s8v*)(pw2b + (size_t)kb * 8192 + mf * 512);
    #pragma unroll
    for (int nf = 0; nf < 4; ++nf){
      ulonglong2 pr = mt2[pbase[nf] + ((4 * kb) ^ pm4[nf])];
      BU bu; bu.d[0] = pr.x; bu.d[1] = pr.y;
      #pragma unroll
      for (int mf = 0; mf < 4; ++mf)
        acc[mf][nf] = __builtin_amdgcn_mfma_f32_16x16x32_bf16(A[mf], bu.v, acc[mf][nf], 0, 0, 0);
    }
  }
  __syncthreads();                    // done reading n1 tile
  u64 pm[4][4];
  #pragma unroll
  for (int mf = 0; mf < 4; ++mf){
    const int fb = w * 64 + mf * 16 + g * 4;
    const float4 bb = *(const float4*)&bias_s[256 + fb];
    #pragma unroll
    for (int nf = 0; nf < 4; ++nf){
      int n = nb + nf * 16 + li;
      int nc = (n >= NN) ? NN - 1 : n;
      float4 hv = *(float4*)(h + (size_t)nc * HH + fb);
      float o0 = hv.x + acc[mf][nf][0] + bb.x;
      float o1 = hv.y + acc[mf][nf][1] + bb.y;
      float o2 = hv.z + acc[mf][nf][2] + bb.z;
      float o3 = hv.w + acc[mf][nf][3] + bb.w;
      pm[mf][nf] = pack4bf(o0, o1, o2, o3);
      if (n < NN){
        *(float4*)(h + (size_t)n * HH + fb) = make_float4(o0, o1, o2, o3);
        *(u64*)(hb + (size_t)n * HH + fb) = pm[mf][nf];
      }
    }
  }
  if (EMIT_PAB){
    #pragma unroll
    for (int nf = 0; nf < 4; ++nf){
      ulonglong2 t0; t0.x = pm[0][nf]; t0.y = pm[1][nf];
      ulonglong2 t1; t1.x = pm[2][nf]; t1.y = pm[3][nf];
      mt2[pbase[nf] + ((8 * w)     ^ pm4[nf])] = t0;
      mt2[pbase[nf] + ((8 * w + 4) ^ pm4[nf])] = t1;
    }
    __syncthreads();
    const u16* pwn = pw1n + ((size_t)(w * 4) * 64 + l) * 8;
    #pragma unroll
    for (int pass = 0; pass < 2; ++pass){
      #pragma unroll
      for (int a = 0; a < 4; ++a)
        #pragma unroll
        for (int b = 0; b < 4; ++b) acc[a][b] = (f4v){0.f,0.f,0.f,0.f};
      const u16* pwp = pwn + (size_t)(pass * 8) * 8192;
      #pragma unroll 4
      for (int kb = 0; kb < 8; ++kb){
        s8v A[4];
        #pragma unroll
        for (int mf = 0; mf < 4; ++mf) A[mf] = *(const s8v*)(pwp + (size_t)kb * 8192 + mf * 512);
        #pragma unroll
        for (int nf = 0; nf < 4; ++nf){
          ulonglong2 pr = mt2[pbase[nf] + ((4 * kb) ^ pm4[nf])];
          BU bu; bu.d[0] = pr.x; bu.d[1] = pr.y;
          #pragma unroll
          for (int mf = 0; mf < 4; ++mf)
            acc[mf][nf] = __builtin_amdgcn_mfma_f32_16x16x32_bf16(A[mf], bu.v, acc[mf][nf], 0, 0, 0);
        }
      }
      u16* dst = pass ? Pbb : Pab;
      #pragma unroll
      for (int mf = 0; mf < 4; ++mf){
        const int fb = w * 64 + mf * 16 + g * 4;
        float c0 = 0.f, c1 = 0.f, c2 = 0.f, c3 = 0.f;
        if (!pass){ c0 = b1n[fb]; c1 = b1n[fb+1]; c2 = b1n[fb+2]; c3 = b1n[fb+3]; }
        #pragma unroll
        for (int nf = 0; nf < 4; ++nf){
          int n = nb + nf * 16 + li;
          if (n < NN)
            *(u64*)(dst + (size_t)n * HH + fb) =
              pack4bf(acc[mf][nf][0] + c0, acc[mf][nf][1] + c1,
                      acc[mf][nf][2] + c2, acc[mf][nf][3] + c3);
        }
      }
    }
  }
}

// ---------------- resblock + head ----------------
__global__ __launch_bounds__(256) void final_kernel(
    const float* __restrict__ z, const float* __restrict__ rw1, const float* __restrict__ rb1,
    const float* __restrict__ rw2, const float* __restrict__ rb2,
    const float* __restrict__ hw, const float* __restrict__ hbs, float* __restrict__ out){
  __shared__ float zr[272], t1[256], t2[272];
  const int b = blockIdx.x, tid = threadIdx.x;
  for (int i = tid; i < 272; i += 256) zr[i] = z[(size_t)b * 272 + i];
  __syncthreads();
  {
    float a = rb1[tid];
    for (int k = 0; k < 272; ++k) a += zr[k] * rw1[(size_t)k * 256 + tid];
    t1[tid] = siluf(a);
  }
  __syncthreads();
  for (int i = tid; i < 272; i += 256){
    float a = rb2[i] + zr[i];
    for (int k = 0; k < 256; ++k) a += t1[k] * rw2[(size_t)k * 272 + i];
    t2[i] = a;
  }
  __syncthreads();
  for (int p = tid; p < 2000; p += 256){
    float a = hbs[p];
    for (int k = 0; k < 272; ++k) a += t2[k] * hw[(size_t)k * 2000 + p];
    out[(size_t)b * 2000 + p] = a;
  }
}

extern "C" void kernel_launch(void* const* d_in, const int* in_sizes, int n_in,
                              void* d_out, int out_size, void* d_ws, size_t ws_size,
                              hipStream_t stream){
  const float* x        = (const float*)d_in[0];
  const float* pos      = (const float*)d_in[1];
  const float* eattr    = (const float*)d_in[2];
  const float* fragl    = (const float*)d_in[3];
  const float* addf     = (const float*)d_in[4];
  const int*   ei       = (const int*)d_in[5];
  const int*   batch    = (const int*)d_in[6];
  const float* emb_in_w = (const float*)d_in[7];
  const float* emb_in_b = (const float*)d_in[8];
  const float* edge_w1  = (const float*)d_in[9];
  const float* edge_b1  = (const float*)d_in[10];
  const float* edge_w2  = (const float*)d_in[11];
  const float* edge_b2  = (const float*)d_in[12];
  const float* node_w1  = (const float*)d_in[13];
  const float* node_b1  = (const float*)d_in[14];
  const float* node_w2  = (const float*)d_in[15];
  const float* node_b2  = (const float*)d_in[16];
  const float* coord_w1 = (const float*)d_in[17];
  const float* coord_b1 = (const float*)d_in[18];
  const float* coord_w2 = (const float*)d_in[19];
  const float* emb_out_w= (const float*)d_in[20];
  const float* emb_out_b= (const float*)d_in[21];
  const float* res_w1   = (const float*)d_in[22];
  const float* res_b1   = (const float*)d_in[23];
  const float* res_w2   = (const float*)d_in[24];
  const float* res_b2   = (const float*)d_in[25];
  const float* head_w   = (const float*)d_in[26];
  const float* head_b   = (const float*)d_in[27];

  char* ws = (char*)d_ws;
  size_t off = 0;
  auto alloc = [&](size_t bytes) -> void* {
    void* p = ws + off;
    off += (bytes + 255) & ~(size_t)255;
    return p;
  };
  float*  h      = (float*)alloc((size_t)NN * HH * 4);
  float*  agg    = (float*)alloc((size_t)NN * HH * 4);
  u16*    hb     = (u16*)  alloc((size_t)NN * HH * 2);
  u16*    Pab    = (u16*)  alloc((size_t)NN * HH * 2);
  u16*    Pbb    = (u16*)  alloc((size_t)NN * HH * 2);
  float*  ho     = (float*)alloc((size_t)NN * HH * 4);
  float4* coordb = (float4*)alloc((size_t)NN * 16);
  float*  cacc   = (float*)alloc((size_t)NN * 16);
  float*  z      = (float*)alloc((size_t)BB * 272 * 4);
  u16*    packed = (u16*)  alloc((size_t)7680 * 256 * 2);
  u16*    ea_s   = (u16*)  alloc((size_t)EE * 16 * 2);
  int*    icnt   = (int*)  alloc((size_t)NN * 4);
  int*    iscan  = (int*)  alloc((size_t)NN * 4);
  int*    rstart = (int*)  alloc((size_t)NN * 4);
  int*    cursor = (int*)  alloc((size_t)NN * 4);
  int*    bsum   = (int*)  alloc((size_t)128 * 4);
  int*    bstart = (int*)  alloc((size_t)(BB + 1) * 4);
  int*    seid   = (int*)  alloc((size_t)EE * 4);
  int*    srow   = (int*)  alloc((size_t)EE * 4);
  int*    scol   = (int*)  alloc((size_t)EE * 4);
  if (off > ws_size) return;

  u16* pk_embin  = packed;
  u16* pk_embout = packed + 32768 + (size_t)4 * 466944;
  auto pk_ew1 = [&](int l){ return packed + 32768 + (size_t)l * 466944; };
  auto pk_ew2 = [&](int l){ return pk_ew1(l) + 139264; };
  auto pk_cw1 = [&](int l){ return pk_ew1(l) + 204800; };
  auto pk_nw1 = [&](int l){ return pk_ew1(l) + 270336; };
  auto pk_nw2 = [&](int l){ return pk_ew1(l) + 401408; };

  pack_kernel<<<16, 256, 0, stream>>>(emb_in_w, pk_embin, 128, 4, 0);
  for (int l = 0; l < 4; ++l){
    pack_kernel<<<68, 256, 0, stream>>>(edge_w1 + (size_t)l * 529 * 256, pk_ew1(l), 529, 17, 1);
    pack_kernel<<<32, 256, 0, stream>>>(edge_w2 + (size_t)l * 65536,     pk_ew2(l), 256, 8, 0);
    pack_kernel<<<32, 256, 0, stream>>>(coord_w1 + (size_t)l * 65536,    pk_cw1(l), 256, 8, 0);
    pack_kernel<<<64, 256, 0, stream>>>(node_w1 + (size_t)l * 131072,    pk_nw1(l), 512, 16, 0);
    pack_kernel<<<32, 256, 0, stream>>>(node_w2 + (size_t)l * 65536,     pk_nw2(l), 256, 8, 0);
  }
  pack_kernel<<<32, 256, 0, stream>>>(emb_out_w, pk_embout, 256, 8, 0);

  // ---- one-time edge sort by row + sorted eattr + per-graph ranges
  const int NB = (NN + 255) / 256;   // 79
  hipMemsetAsync(icnt,   0, (size_t)NN * 4, stream);
  hipMemsetAsync(cursor, 0, (size_t)NN * 4, stream);
  icnt_kernel<<<(EE + 255) / 256, 256, 0, stream>>>(ei, icnt);
  iscan_block<<<NB, 256, 0, stream>>>(icnt, iscan, bsum);
  iscan_top<<<1, 64, 0, stream>>>(bsum, NB);
  iscan_fix<<<NB, 256, 0, stream>>>(icnt, iscan, bsum, rstart);
  scatter_kernel<<<(EE + 255) / 256, 256, 0, stream>>>(ei, rstart, cursor, seid, srow, scol);
  sort_ea_kernel<<<(EE * 16 + 255) / 256, 256, 0, stream>>>(eattr, seid, ea_s);
  bstart_kernel<<<NB, 256, 0, stream>>>(batch, bstart);

  coord_init_kernel<<<79, 256, 0, stream>>>(pos, coordb);
  emb_in_kernel<<<313, 256, 0, stream>>>(x, pk_embin, emb_in_b, h, hb,
                                         pk_ew1(0), edge_b1, Pab, Pbb);

  for (int l = 0; l < 4; ++l){
    hipMemsetAsync(cacc, 0, (size_t)NN * 16, stream);
    hipMemsetAsync(agg,  0, (size_t)NN * HH * 4, stream);
    edge_kernel<<<5000, 512, 0, stream>>>(Pab, Pbb, coordb, srow, scol, ea_s,
        pk_ew1(l), pk_ew2(l), pk_cw1(l),
        edge_b2 + l * 256, coord_b1 + l * 256, coord_w2 + l * 256,
        agg, cacc);
    if (l < 3)
      node_pab_kernel<true><<<313, 256, 0, stream>>>(h, hb, agg, pk_nw1(l), pk_nw2(l),
          node_b1 + l * 256, node_b2 + l * 256,
          pk_ew1(l + 1), edge_b1 + (l + 1) * 256, Pab, Pbb,
          coordb, cacc, icnt);
    else
      node_pab_kernel<false><<<313, 256, 0, stream>>>(h, hb, agg, pk_nw1(l), pk_nw2(l),
          node_b1 + l * 256, node_b2 + l * 256,
          pk_ew1(0), edge_b1, Pab, Pbb,
          coordb, cacc, icnt);
  }

  emb_out_kernel<<<313, 256, 0, stream>>>(hb, pk_embout, emb_out_b, ho);
  pool_csr_kernel<<<BB * 4, 64, 0, stream>>>(ho, bstart, fragl, addf, z);
  final_kernel<<<128, 256, 0, stream>>>(z, res_w1, res_b1, res_w2, res_b2, head_w, head_b,
                                        (float*)d_out);
}

// Round 13
// 1310.019 us; speedup vs baseline: 1.2204x; 1.0026x over previous
//
#include <hip/hip_runtime.h>

typedef unsigned short u16;
typedef unsigned int   u32;
typedef unsigned long long u64;
typedef __attribute__((ext_vector_type(8))) short s8v;   // 8 bf16 (4 VGPRs) MFMA operand
typedef __attribute__((ext_vector_type(4))) float f4v;   // MFMA accumulator

#define NN 20000
#define EE 320000
#define BB 128
#define HH 256

union BU { u64 d[2]; s8v v; };

__device__ __forceinline__ u16 f2bf(float f){
  u32 u = __float_as_uint(f);
  return (u16)((u + 0x7FFFu + ((u >> 16) & 1u)) >> 16);   // RNE
}
__device__ __forceinline__ float bf2f(u16 u){ return __uint_as_float((u32)u << 16); }
__device__ __forceinline__ u32 cvt2(float a, float b){
  u32 r; asm("v_cvt_pk_bf16_f32 %0, %1, %2" : "=v"(r) : "v"(a), "v"(b)); return r;
}
__device__ __forceinline__ u64 pack4bf(float a, float b, float c, float d){
  return (u64)cvt2(a, b) | ((u64)cvt2(c, d) << 32);
}
// silu via v_rcp (1 instr); 1-ulp rcp error << bf16 rounding
__device__ __forceinline__ float siluf(float v){
  return v * __builtin_amdgcn_rcpf(1.0f + __expf(-v));
}

// ---------------- weight packing: W [K][256] f32 -> A-fragment blob (W^T), bf16 ----------------
// remap=1 (edge_w1): new-k 512..527 <- old 513..528 (eattr), new-k 528 <- old 512 (radial)
__global__ void pack_kernel(const float* __restrict__ src, u16* __restrict__ dst, int K, int KB, int remap){
  int t = blockIdx.x * 256 + threadIdx.x;
  if (t >= KB * 1024) return;
  int lane = t & 63, mf = (t >> 6) & 15, kb = t >> 10;
  int g = lane >> 4, li = lane & 15;
  int m = mf * 16 + li;
  u16 o[8];
  #pragma unroll
  for (int j = 0; j < 8; ++j){
    int k = kb * 32 + ((j < 4) ? (g * 4 + j) : (16 + g * 4 + (j - 4)));
    int ks = k;
    if (remap){ if (k >= 512 && k < 528) ks = k + 1; else if (k == 528) ks = 512; }
    o[j] = (k < K) ? f2bf(src[(size_t)ks * 256 + m]) : (u16)0;
  }
  u16* d = dst + ((size_t)(kb * 16 + mf) * 64 + lane) * 8;
  *(u64*)(d)     = (u64)o[0] | ((u64)o[1] << 16) | ((u64)o[2] << 32) | ((u64)o[3] << 48);
  *(u64*)(d + 4) = (u64)o[4] | ((u64)o[5] << 16) | ((u64)o[6] << 32) | ((u64)o[7] << 48);
}

// ---------------- edge sort by destination row (one-time per launch) ----------------
__global__ void icnt_kernel(const int* __restrict__ ei, int* __restrict__ icnt){
  int t = blockIdx.x * 256 + threadIdx.x;
  if (t < EE) atomicAdd(&icnt[ei[t]], 1);
}
__global__ void iscan_block(const int* __restrict__ icnt, int* __restrict__ iscan, int* __restrict__ bsum){
  __shared__ int s[256];
  int i = blockIdx.x * 256 + threadIdx.x;
  int v = (i < NN) ? icnt[i] : 0;
  s[threadIdx.x] = v; __syncthreads();
  #pragma unroll
  for (int d = 1; d < 256; d <<= 1){
    int t = (threadIdx.x >= d) ? s[threadIdx.x - d] : 0;
    __syncthreads();
    s[threadIdx.x] += t;
    __syncthreads();
  }
  if (i < NN) iscan[i] = s[threadIdx.x];
  if (threadIdx.x == 255) bsum[blockIdx.x] = s[255];
}
__global__ void iscan_top(int* __restrict__ bsum, int nb){
  if (blockIdx.x == 0 && threadIdx.x == 0){
    int acc = 0;
    for (int i = 0; i < nb; ++i){ int t = bsum[i]; bsum[i] = acc; acc += t; }
  }
}
__global__ void iscan_fix(const int* __restrict__ icnt, const int* __restrict__ iscan,
                          const int* __restrict__ bsum, int* __restrict__ rstart){
  int i = blockIdx.x * 256 + threadIdx.x;
  if (i < NN) rstart[i] = bsum[blockIdx.x] + iscan[i] - icnt[i];
}
__global__ void scatter_kernel(const int* __restrict__ ei, const int* __restrict__ rstart,
                               int* __restrict__ cursor, int* __restrict__ seid,
                               int* __restrict__ srow, int* __restrict__ scol){
  int e = blockIdx.x * 256 + threadIdx.x;
  if (e < EE){
    int r = ei[e];
    int p = rstart[r] + atomicAdd(&cursor[r], 1);
    seid[p] = e; srow[p] = r; scol[p] = ei[EE + e];
  }
}
// eattr gathered into sorted order, bf16 (one-time)
__global__ void sort_ea_kernel(const float* __restrict__ eattr, const int* __restrict__ seid,
                               u16* __restrict__ es){
  int t = blockIdx.x * 256 + threadIdx.x;
  if (t < EE * 16){
    int p = t >> 4, j = t & 15;
    es[t] = f2bf(eattr[(size_t)seid[p] * 16 + j]);
  }
}
// per-graph node ranges from the SORTED batch array (run once)
__global__ void bstart_kernel(const int* __restrict__ batch, int* __restrict__ bstart){
  int n = blockIdx.x * 256 + threadIdx.x;
  if (n >= NN) return;
  int b = batch[n];
  if (n == 0){ for (int x = 0; x <= b; ++x) bstart[x] = 0; }
  else {
    int pb = batch[n - 1];
    for (int x = pb + 1; x <= b; ++x) bstart[x] = n;
  }
  if (n == NN - 1) bstart[BB] = NN;
}

// ---------------- small utility kernels ----------------
__global__ void coord_init_kernel(const float* __restrict__ pos, float4* __restrict__ coord){
  int t = blockIdx.x * 256 + threadIdx.x;
  if (t < NN) coord[t] = make_float4(pos[3*t], pos[3*t+1], pos[3*t+2], 0.f);
}

// ---------------- emb_in (+ fused pab for layer 0) ----------------
// LDS pair layout: chunk c=(a,b4,g) stored as ulonglong2 at mt2[e*32 + ((a*4+g)^(e&7))];
// pbase = e*32 + (g^(e&3)), pm4 = e&4; index(a) = pbase + ((4a)^pm4).
__global__ __launch_bounds__(256) void emb_in_kernel(
    const float* __restrict__ x, const u16* __restrict__ pw,
    const float* __restrict__ bias, float* __restrict__ h, u16* __restrict__ hb,
    const u16* __restrict__ pw1n, const float* __restrict__ b1n,
    u16* __restrict__ Pab, u16* __restrict__ Pbb){
  __shared__ ulonglong2 mt2[2048];
  const int tid = threadIdx.x;
  const int w = tid >> 6, l = tid & 63, g = l >> 4, li = l & 15;
  const int nb = blockIdx.x * 64;
  const float* xp[4];
  int pbase[4], pm4[4];
  #pragma unroll
  for (int nf = 0; nf < 4; ++nf){
    int n = nb + nf * 16 + li; if (n >= NN) n = NN - 1;
    xp[nf] = x + (size_t)n * 128 + g * 4;
    int e = nf * 16 + li;
    pbase[nf] = e * 32 + (g ^ (e & 3));
    pm4[nf] = e & 4;
  }
  f4v acc[4][4];
  #pragma unroll
  for (int a = 0; a < 4; ++a)
    #pragma unroll
    for (int b = 0; b < 4; ++b) acc[a][b] = (f4v){0.f,0.f,0.f,0.f};
  const u16* pwb = pw + ((size_t)(w * 4) * 64 + l) * 8;
  #pragma unroll
  for (int kb = 0; kb < 4; ++kb){
    s8v A[4];
    #pragma unroll
    for (int mf = 0; mf < 4; ++mf) A[mf] = *(const s8v*)(pwb + (size_t)kb * 8192 + mf * 512);
    #pragma unroll
    for (int nf = 0; nf < 4; ++nf){
      float4 fa = *(const float4*)(xp[nf] + kb * 32);
      float4 fb = *(const float4*)(xp[nf] + kb * 32 + 16);
      BU bu;
      bu.d[0] = pack4bf(fa.x, fa.y, fa.z, fa.w);
      bu.d[1] = pack4bf(fb.x, fb.y, fb.z, fb.w);
      #pragma unroll
      for (int mf = 0; mf < 4; ++mf)
        acc[mf][nf] = __builtin_amdgcn_mfma_f32_16x16x32_bf16(A[mf], bu.v, acc[mf][nf], 0, 0, 0);
    }
  }
  u64 pm[4][4];
  #pragma unroll
  for (int mf = 0; mf < 4; ++mf){
    const int fb = w * 64 + mf * 16 + g * 4;
    float b0 = bias[fb], b1 = bias[fb+1], b2 = bias[fb+2], b3 = bias[fb+3];
    #pragma unroll
    for (int nf = 0; nf < 4; ++nf){
      int n = nb + nf * 16 + li;
      float o0 = acc[mf][nf][0] + b0, o1 = acc[mf][nf][1] + b1;
      float o2 = acc[mf][nf][2] + b2, o3 = acc[mf][nf][3] + b3;
      pm[mf][nf] = pack4bf(o0, o1, o2, o3);
      if (n < NN){
        *(float4*)(h + (size_t)n * HH + fb) = make_float4(o0, o1, o2, o3);
        *(u64*)(hb + (size_t)n * HH + fb) = pm[mf][nf];
      }
    }
  }
  #pragma unroll
  for (int nf = 0; nf < 4; ++nf){
    ulonglong2 t0; t0.x = pm[0][nf]; t0.y = pm[1][nf];
    ulonglong2 t1; t1.x = pm[2][nf]; t1.y = pm[3][nf];
    mt2[pbase[nf] + ((8 * w)     ^ pm4[nf])] = t0;
    mt2[pbase[nf] + ((8 * w + 4) ^ pm4[nf])] = t1;
  }
  __syncthreads();
  const u16* pwn = pw1n + ((size_t)(w * 4) * 64 + l) * 8;
  #pragma unroll
  for (int pass = 0; pass < 2; ++pass){
    #pragma unroll
    for (int a = 0; a < 4; ++a)
      #pragma unroll
      for (int b = 0; b < 4; ++b) acc[a][b] = (f4v){0.f,0.f,0.f,0.f};
    const u16* pwp = pwn + (size_t)(pass * 8) * 8192;
    #pragma unroll 4
    for (int kb = 0; kb < 8; ++kb){
      s8v A[4];
      #pragma unroll
      for (int mf = 0; mf < 4; ++mf) A[mf] = *(const s8v*)(pwp + (size_t)kb * 8192 + mf * 512);
      #pragma unroll
      for (int nf = 0; nf < 4; ++nf){
        ulonglong2 pr = mt2[pbase[nf] + ((4 * kb) ^ pm4[nf])];
        BU bu; bu.d[0] = pr.x; bu.d[1] = pr.y;
        #pragma unroll
        for (int mf = 0; mf < 4; ++mf)
          acc[mf][nf] = __builtin_amdgcn_mfma_f32_16x16x32_bf16(A[mf], bu.v, acc[mf][nf], 0, 0, 0);
      }
    }
    u16* dst = pass ? Pbb : Pab;
    #pragma unroll
    for (int mf = 0; mf < 4; ++mf){
      const int fb = w * 64 + mf * 16 + g * 4;
      float c0 = 0.f, c1 = 0.f, c2 = 0.f, c3 = 0.f;
      if (!pass){ c0 = b1n[fb]; c1 = b1n[fb+1]; c2 = b1n[fb+2]; c3 = b1n[fb+3]; }
      #pragma unroll
      for (int nf = 0; nf < 4; ++nf){
        int n = nb + nf * 16 + li;
        if (n < NN)
          *(u64*)(dst + (size_t)n * HH + fb) =
            pack4bf(acc[mf][nf][0] + c0, acc[mf][nf][1] + c1,
                    acc[mf][nf][2] + c2, acc[mf][nf][3] + c3);
      }
    }
  }
}

// ---------------- emb_out: ho = h @ emb_out_w + b ----------------
__global__ __launch_bounds__(256) void emb_out_kernel(
    const u16* __restrict__ hb, const u16* __restrict__ pw,
    const float* __restrict__ bias, float* __restrict__ ho){
  const int tid = threadIdx.x;
  const int w = tid >> 6, l = tid & 63, g = l >> 4, li = l & 15;
  const int nb = blockIdx.x * 64;
  const u16* hp[4];
  #pragma unroll
  for (int nf = 0; nf < 4; ++nf){
    int n = nb + nf * 16 + li; if (n >= NN) n = NN - 1;
    hp[nf] = hb + (size_t)n * HH + g * 4;
  }
  f4v acc[4][4];
  #pragma unroll
  for (int a = 0; a < 4; ++a)
    #pragma unroll
    for (int b = 0; b < 4; ++b) acc[a][b] = (f4v){0.f,0.f,0.f,0.f};
  const u16* pwb = pw + ((size_t)(w * 4) * 64 + l) * 8;
  #pragma unroll 4
  for (int kb = 0; kb < 8; ++kb){
    s8v A[4];
    #pragma unroll
    for (int mf = 0; mf < 4; ++mf) A[mf] = *(const s8v*)(pwb + (size_t)kb * 8192 + mf * 512);
    #pragma unroll
    for (int nf = 0; nf < 4; ++nf){
      BU bu;
      bu.d[0] = *(const u64*)(hp[nf] + kb * 32);
      bu.d[1] = *(const u64*)(hp[nf] + kb * 32 + 16);
      #pragma unroll
      for (int mf = 0; mf < 4; ++mf)
        acc[mf][nf] = __builtin_amdgcn_mfma_f32_16x16x32_bf16(A[mf], bu.v, acc[mf][nf], 0, 0, 0);
    }
  }
  #pragma unroll
  for (int mf = 0; mf < 4; ++mf){
    const int fb = w * 64 + mf * 16 + g * 4;
    float b0 = bias[fb], b1 = bias[fb+1], b2 = bias[fb+2], b3 = bias[fb+3];
    #pragma unroll
    for (int nf = 0; nf < 4; ++nf){
      int n = nb + nf * 16 + li;
      if (n < NN)
        *(float4*)(ho + (size_t)n * HH + fb) =
          make_float4(acc[mf][nf][0] + b0, acc[mf][nf][1] + b1,
                      acc[mf][nf][2] + b2, acc[mf][nf][3] + b3);
    }
  }
}

// ---------------- max-pool over contiguous per-graph node ranges + build z ----------------
__global__ __launch_bounds__(64) void pool_csr_kernel(
    const float* __restrict__ ho, const int* __restrict__ bstart,
    const float* __restrict__ fragl, const float* __restrict__ addf, float* __restrict__ z){
  const int b = blockIdx.x >> 2, q = blockIdx.x & 3;
  const int f = q * 64 + threadIdx.x;
  const int s = bstart[b], e = bstart[b + 1];
  const float* p = ho + (size_t)s * HH + f;
  float m0 = -3.0e38f, m1 = -3.0e38f;
  int n = s;
  for (; n + 1 < e; n += 2){ m0 = fmaxf(m0, p[0]); m1 = fmaxf(m1, p[HH]); p += 2 * HH; }
  if (n < e) m0 = fmaxf(m0, p[0]);
  z[(size_t)b * 272 + f] = fmaxf(m0, m1);
  if (q == 0 && threadIdx.x < 16){
    int j = threadIdx.x;
    float v = (j < 8) ? fragl[b * 8 + j] : addf[b * 8 + (j - 8)];
    z[(size_t)b * 272 + 256 + j] = v;
  }
}

// ---------------- edge kernel: 64 SORTED edges/block, 512 threads (8 waves x 32 feats) ----------------
// Pa/Pb injected via identity-A MFMAs (zero-VALU, bit-identical to scalar adds);
// in-block row aggregation over m2 LDS tile split across all 512 threads.
__global__ __launch_bounds__(512, 4) void edge_kernel(
    const u16* __restrict__ Pab, const u16* __restrict__ Pbb,
    const float4* __restrict__ coord,
    const int* __restrict__ srow, const int* __restrict__ scol,
    const u16* __restrict__ eattr_s,
    const u16* __restrict__ pw1, const u16* __restrict__ pw2, const u16* __restrict__ pw3,
    const float* __restrict__ b2, const float* __restrict__ cb1, const float* __restrict__ cw2,
    float* __restrict__ agg, float* __restrict__ cacc){
  __shared__ ulonglong2 mt2[2048];    // 32KB pair tile [64 edges][32 pairs]
  __shared__ float4 dif[64];
  __shared__ int rows_s[64];
  __shared__ int cols_s[64];
  __shared__ float bias_s[768];       // b2 | cb1 | cw2
  __shared__ float cpart[8][64];
  __shared__ int prevrow_s, nextrow_s;

  const int tid = threadIdx.x;
  const int w = tid >> 6, l = tid & 63, g = l >> 4, li = l & 15;
  const int wg = (blockIdx.x & 7) * 625 + (blockIdx.x >> 3);
  const int eb = wg * 64;

  if (tid < 64){
    int sp = eb + tid;
    int r = srow[sp], c = scol[sp];
    rows_s[tid] = r; cols_s[tid] = c;
    float4 ca = coord[r], cb = coord[c];
    float dx = ca.x - cb.x, dy = ca.y - cb.y, dz = ca.z - cb.z;
    float rad = dx*dx + dy*dy + dz*dz;
    dif[tid] = make_float4(dx, dy, dz, rad);
  }
  if (tid == 64) prevrow_s = (eb > 0) ? srow[eb - 1] : -1;
  if (tid == 65) nextrow_s = (eb + 64 < EE) ? srow[eb + 64] : -1;
  for (int i = tid; i < 768; i += 512){
    float v;
    if      (i < 256) v = b2[i];
    else if (i < 512) v = cb1[i - 256];
    else              v = cw2[i - 512];
    bias_s[i] = v;
  }
  __syncthreads();

  const u16* paP[4]; const u16* pbP[4];
  int pbase[4], pm4[4], wrI[4];
  #pragma unroll
  for (int nf = 0; nf < 4; ++nf){
    int e = nf * 16 + li;
    paP[nf] = Pab + (size_t)rows_s[e] * HH;
    pbP[nf] = Pbb + (size_t)cols_s[e] * HH;
    pbase[nf] = e * 32 + (g ^ (e & 3));
    pm4[nf] = e & 4;
    wrI[nf] = pbase[nf] + ((4 * w) ^ pm4[nf]);
  }

  // ---- EARLY Pa/Pb gather issue (bf16, 8B/frag; latency hides under tail MFMA)
  u64 pa[2][4], pb[2][4];
  #pragma unroll
  for (int mf = 0; mf < 2; ++mf){
    const int fb = w * 32 + mf * 16 + g * 4;
    #pragma unroll
    for (int nf = 0; nf < 4; ++nf){
      pa[mf][nf] = *(const u64*)(paP[nf] + fb);
      pb[mf][nf] = *(const u64*)(pbP[nf] + fb);
    }
  }

  const u16* pw1b = pw1 + ((size_t)(w * 2) * 64 + l) * 8;
  const u16* pw2b = pw2 + ((size_t)(w * 2) * 64 + l) * 8;
  const u16* pw3b = pw3 + ((size_t)(w * 2) * 64 + l) * 8;

  // identity A-fragments for Pa/Pb injection: A0=[I16;0], A1=[0;I16] over this
  // wave's k-range; at most one slot per lane holds bf16(1.0)=0x3F80.
  BU ai0, ai1;
  {
    u64 idlo = 0;
    int d = li - g * 4;
    if (d >= 0 && d < 4) idlo = 0x3F80ULL << (16 * d);
    ai0.d[0] = idlo; ai0.d[1] = 0;
    ai1.d[0] = 0;    ai1.d[1] = idlo;
  }

  f4v acc[2][4];
  #pragma unroll
  for (int a = 0; a < 2; ++a)
    #pragma unroll
    for (int b = 0; b < 4; ++b) acc[a][b] = (f4v){0.f,0.f,0.f,0.f};

  // ---- tail MFMA: k 512..527 = eattr_s (aligned 8B), k 528 = radial (hi half, g==0)
  {
    s8v at[2];
    #pragma unroll
    for (int mf = 0; mf < 2; ++mf) at[mf] = *(const s8v*)(pw1b + (size_t)16 * 8192 + mf * 512);
    #pragma unroll
    for (int nf = 0; nf < 4; ++nf){
      int e = nf * 16 + li;
      BU bu;
      bu.d[0] = *(const u64*)(eattr_s + (size_t)(eb + e) * 16 + g * 4);
      bu.d[1] = (g == 0) ? (u64)f2bf(dif[e].w) : 0;
      #pragma unroll
      for (int mf = 0; mf < 2; ++mf)
        acc[mf][nf] = __builtin_amdgcn_mfma_f32_16x16x32_bf16(at[mf], bu.v, acc[mf][nf], 0, 0, 0);
    }
  }
  // ---- Pa/Pb injection on the matrix pipe (exact: one nonzero product per output)
  #pragma unroll
  for (int nf = 0; nf < 4; ++nf){
    BU bp; bp.d[0] = pa[0][nf]; bp.d[1] = pa[1][nf];
    acc[0][nf] = __builtin_amdgcn_mfma_f32_16x16x32_bf16(ai0.v, bp.v, acc[0][nf], 0, 0, 0);
    acc[1][nf] = __builtin_amdgcn_mfma_f32_16x16x32_bf16(ai1.v, bp.v, acc[1][nf], 0, 0, 0);
    BU bq; bq.d[0] = pb[0][nf]; bq.d[1] = pb[1][nf];
    acc[0][nf] = __builtin_amdgcn_mfma_f32_16x16x32_bf16(ai0.v, bq.v, acc[0][nf], 0, 0, 0);
    acc[1][nf] = __builtin_amdgcn_mfma_f32_16x16x32_bf16(ai1.v, bq.v, acc[1][nf], 0, 0, 0);
  }

  // ---- m1 = silu(acc) -> b128 tile write
  #pragma unroll
  for (int nf = 0; nf < 4; ++nf){
    ulonglong2 t;
    t.x = pack4bf(siluf(acc[0][nf][0]), siluf(acc[0][nf][1]), siluf(acc[0][nf][2]), siluf(acc[0][nf][3]));
    t.y = pack4bf(siluf(acc[1][nf][0]), siluf(acc[1][nf][1]), siluf(acc[1][nf][2]), siluf(acc[1][nf][3]));
    mt2[wrI[nf]] = t;
  }
  __syncthreads();

  // ---- GEMM2: m2 = silu(m1 @ W2 + b2)
  #pragma unroll
  for (int a = 0; a < 2; ++a)
    #pragma unroll
    for (int b = 0; b < 4; ++b) acc[a][b] = (f4v){0.f,0.f,0.f,0.f};
  #pragma unroll
  for (int s = 0; s < 8; ++s){
    s8v A[2];
    #pragma unroll
    for (int mf = 0; mf < 2; ++mf) A[mf] = *(const s8v*)(pw2b + (size_t)s * 8192 + mf * 512);
    #pragma unroll
    for (int nf = 0; nf < 4; ++nf){
      ulonglong2 pr = mt2[pbase[nf] + ((4 * s) ^ pm4[nf])];
      BU bu; bu.d[0] = pr.x; bu.d[1] = pr.y;
      #pragma unroll
      for (int mf = 0; mf < 2; ++mf)
        acc[mf][nf] = __builtin_amdgcn_mfma_f32_16x16x32_bf16(A[mf], bu.v, acc[mf][nf], 0, 0, 0);
    }
  }
  u64 pm2[2][4];
  #pragma unroll
  for (int mf = 0; mf < 2; ++mf){
    const int fb = w * 32 + mf * 16 + g * 4;
    const float4 bb = *(const float4*)&bias_s[fb];
    #pragma unroll
    for (int nf = 0; nf < 4; ++nf)
      pm2[mf][nf] = pack4bf(siluf(acc[mf][nf][0] + bb.x),
                            siluf(acc[mf][nf][1] + bb.y),
                            siluf(acc[mf][nf][2] + bb.z),
                            siluf(acc[mf][nf][3] + bb.w));
  }
  __syncthreads();                    // all waves done reading m1
  #pragma unroll
  for (int nf = 0; nf < 4; ++nf){
    ulonglong2 t; t.x = pm2[0][nf]; t.y = pm2[1][nf];
    mt2[wrI[nf]] = t;
  }
  __syncthreads();                    // m2 tile ready (stays valid to end of kernel)

  // ---- GEMM3: q = silu(m2 @ CW1 + cb1); c = q . cw2
  #pragma unroll
  for (int a = 0; a < 2; ++a)
    #pragma unroll
    for (int b = 0; b < 4; ++b) acc[a][b] = (f4v){0.f,0.f,0.f,0.f};
  #pragma unroll
  for (int s = 0; s < 8; ++s){
    s8v A[2];
    #pragma unroll
    for (int mf = 0; mf < 2; ++mf) A[mf] = *(const s8v*)(pw3b + (size_t)s * 8192 + mf * 512);
    #pragma unroll
    for (int nf = 0; nf < 4; ++nf){
      ulonglong2 pr = mt2[pbase[nf] + ((4 * s) ^ pm4[nf])];
      BU bu; bu.d[0] = pr.x; bu.d[1] = pr.y;
      #pragma unroll
      for (int mf = 0; mf < 2; ++mf)
        acc[mf][nf] = __builtin_amdgcn_mfma_f32_16x16x32_bf16(A[mf], bu.v, acc[mf][nf], 0, 0, 0);
    }
  }
  float cp4[4] = {0.f, 0.f, 0.f, 0.f};
  #pragma unroll
  for (int mf = 0; mf < 2; ++mf){
    const int fb = w * 32 + mf * 16 + g * 4;
    const float4 cb = *(const float4*)&bias_s[256 + fb];
    const float4 cw = *(const float4*)&bias_s[512 + fb];
    #pragma unroll
    for (int nf = 0; nf < 4; ++nf){
      cp4[nf] += siluf(acc[mf][nf][0] + cb.x) * cw.x;
      cp4[nf] += siluf(acc[mf][nf][1] + cb.y) * cw.y;
      cp4[nf] += siluf(acc[mf][nf][2] + cb.z) * cw.z;
      cp4[nf] += siluf(acc[mf][nf][3] + cb.w) * cw.w;
    }
  }
  #pragma unroll
  for (int nf = 0; nf < 4; ++nf){
    float v = cp4[nf];
    v += __shfl_xor(v, 16, 64);
    v += __shfl_xor(v, 32, 64);
    if (g == 0) cpart[w][nf * 16 + li] = v;
  }
  __syncthreads();

  // ---- cacc: segmented suffix-reduce across the 64 sorted edges, head lanes atomic
  if (tid < 64){
    float c = cpart[0][tid] + cpart[1][tid] + cpart[2][tid] + cpart[3][tid]
            + cpart[4][tid] + cpart[5][tid] + cpart[6][tid] + cpart[7][tid];
    float4 d = dif[tid];
    const int myrow = rows_s[tid];
    float vx = d.x * c, vy = d.y * c, vz = d.z * c;
    #pragma unroll
    for (int dd = 1; dd < 64; dd <<= 1){
      const int rr = __shfl_down(myrow, dd, 64);
      const bool ok = ((tid + dd) < 64) && (rr == myrow);
      float tx = __shfl_down(vx, dd, 64);
      float ty = __shfl_down(vy, dd, 64);
      float tz = __shfl_down(vz, dd, 64);
      if (ok){ vx += tx; vy += ty; vz += tz; }
    }
    if (tid == 0 || rows_s[tid - 1] != myrow){
      atomicAdd(cacc + (size_t)myrow * 4 + 0, vx);
      atomicAdd(cacc + (size_t)myrow * 4 + 1, vy);
      atomicAdd(cacc + (size_t)myrow * 4 + 2, vz);
    }
  }

  // ---- agg: in-block segment-sum of the m2 tile over ALL 512 threads:
  // thread = (feature f, half h); each half covers 32 edges. Interior runs -> store;
  // runs touching a half boundary (incl. block boundaries) -> atomicAdd.
  {
    const int f = tid & 255;
    const int half = tid >> 8;
    const int ebase = half << 5;
    const int slotbase = ((f >> 5) << 2) + ((f >> 2) & 3);  // a*4 + g
    const int off16 = (((f >> 4) & 1) << 2) + (f & 3);       // b4*4 + j
    const u16* mtu = (const u16*)mt2;
    const int prow = half ? rows_s[31] : prevrow_s;
    const int nrow = half ? nextrow_s : rows_s[32];
    float s = 0.f;
    int cur = rows_s[ebase];
    bool first = true;
    #pragma unroll 8
    for (int i = 0; i < 32; ++i){
      int e = ebase + i;
      int r = rows_s[e];
      if (r != cur){
        float* dst = &agg[(size_t)cur * HH + f];
        if (first && cur == prow) atomicAdd(dst, s);
        else *dst = s;
        s = 0.f; cur = r; first = false;
      }
      s += bf2f(mtu[e * 256 + ((slotbase ^ (e & 7)) << 3) + off16]);
    }
    float* dst = &agg[(size_t)cur * HH + f];
    if ((first && cur == prow) || cur == nrow) atomicAdd(dst, s);
    else *dst = s;
  }
}

// ---------------- node kernel (+ fused coord update + next-layer pab) ----------------
// h += MLP([h, agg]); agg consumed as f32 (conversion fused); coordb updated in preamble.
template<bool EMIT_PAB>
__global__ __launch_bounds__(256) void node_pab_kernel(
    float* __restrict__ h, u16* __restrict__ hb, const float* __restrict__ agg,
    const u16* __restrict__ pw1, const u16* __restrict__ pw2,
    const float* __restrict__ b1, const float* __restrict__ b2,
    const u16* __restrict__ pw1n, const float* __restrict__ b1n,
    u16* __restrict__ Pab, u16* __restrict__ Pbb,
    float4* __restrict__ coordb, const float* __restrict__ cacc, const int* __restrict__ icnt){
  __shared__ ulonglong2 mt2[2048];
  __shared__ float bias_s[512];
  const int tid = threadIdx.x;
  const int w = tid >> 6, l = tid & 63, g = l >> 4, li = l & 15;
  const int nb = blockIdx.x * 64;
  // fused coord update for this block's 64 nodes (cacc complete: edge kernel finished)
  if (tid < 64){
    int n = nb + tid;
    if (n < NN){
      float k = fmaxf((float)icnt[n], 1.0f);
      float4 c = coordb[n];
      c.x += cacc[4*n+0] / k; c.y += cacc[4*n+1] / k; c.z += cacc[4*n+2] / k;
      coordb[n] = c;
    }
  }
  for (int i = tid; i < 512; i += 256) bias_s[i] = (i < 256) ? b1[i] : b2[i - 256];
  __syncthreads();

  const u16* hp[4]; const float* ap[4];
  int pbase[4], pm4[4];
  #pragma unroll
  for (int nf = 0; nf < 4; ++nf){
    int n = nb + nf * 16 + li; if (n >= NN) n = NN - 1;
    hp[nf] = hb  + (size_t)n * HH + g * 4;
    ap[nf] = agg + (size_t)n * HH + g * 4;
    int e = nf * 16 + li;
    pbase[nf] = e * 32 + (g ^ (e & 3));
    pm4[nf] = e & 4;
  }
  f4v acc[4][4];
  #pragma unroll
  for (int a = 0; a < 4; ++a)
    #pragma unroll
    for (int b = 0; b < 4; ++b) acc[a][b] = (f4v){0.f,0.f,0.f,0.f};

  const u16* pw1b = pw1 + ((size_t)(w * 4) * 64 + l) * 8;
  #pragma unroll 4
  for (int kb = 0; kb < 8; ++kb){
    s8v A[4];
    #pragma unroll
    for (int mf = 0; mf < 4; ++mf) A[mf] = *(const s8v*)(pw1b + (size_t)kb * 8192 + mf * 512);
    #pragma unroll
    for (int nf = 0; nf < 4; ++nf){
      BU bu;
      bu.d[0] = *(const u64*)(hp[nf] + kb * 32);
      bu.d[1] = *(const u64*)(hp[nf] + kb * 32 + 16);
      #pragma unroll
      for (int mf = 0; mf < 4; ++mf)
        acc[mf][nf] = __builtin_amdgcn_mfma_f32_16x16x32_bf16(A[mf], bu.v, acc[mf][nf], 0, 0, 0);
    }
  }
  #pragma unroll 4
  for (int kb = 8; kb < 16; ++kb){
    s8v A[4];
    #pragma unroll
    for (int mf = 0; mf < 4; ++mf) A[mf] = *(const s8v*)(pw1b + (size_t)kb * 8192 + mf * 512);
    #pragma unroll
    for (int nf = 0; nf < 4; ++nf){
      float4 fa = *(const float4*)(ap[nf] + (kb - 8) * 32);
      float4 fb = *(const float4*)(ap[nf] + (kb - 8) * 32 + 16);
      BU bu;
      bu.d[0] = pack4bf(fa.x, fa.y, fa.z, fa.w);
      bu.d[1] = pack4bf(fb.x, fb.y, fb.z, fb.w);
      #pragma unroll
      for (int mf = 0; mf < 4; ++mf)
        acc[mf][nf] = __builtin_amdgcn_mfma_f32_16x16x32_bf16(A[mf], bu.v, acc[mf][nf], 0, 0, 0);
    }
  }
  #pragma unroll
  for (int nf = 0; nf < 4; ++nf){
    u64 p01[4];
    #pragma unroll
    for (int mf = 0; mf < 4; ++mf){
      const int fb = w * 64 + mf * 16 + g * 4;
      const float4 bb = *(const float4*)&bias_s[fb];
      p01[mf] = pack4bf(siluf(acc[mf][nf][0] + bb.x), siluf(acc[mf][nf][1] + bb.y),
                        siluf(acc[mf][nf][2] + bb.z), siluf(acc[mf][nf][3] + bb.w));
    }
    ulonglong2 t0; t0.x = p01[0]; t0.y = p01[1];
    ulonglong2 t1; t1.x = p01[2]; t1.y = p01[3];
    mt2[pbase[nf] + ((8 * w)     ^ pm4[nf])] = t0;
    mt2[pbase[nf] + ((8 * w + 4) ^ pm4[nf])] = t1;
  }
  __syncthreads();

  #pragma unroll
  for (int a = 0; a < 4; ++a)
    #pragma unroll
    for (int b = 0; b < 4; ++b) acc[a][b] = (f4v){0.f,0.f,0.f,0.f};
  const u16* pw2b = pw2 + ((size_t)(w * 4) * 64 + l) * 8;
  #pragma unroll 4
  for (int kb = 0; kb < 8; ++kb){
    s8v A[4];
    #pragma unroll
    for (int mf = 0; mf < 4; ++mf) A[mf] = *(const s8v*)(pw2b + (size_t)kb * 8192 + mf * 512);
    #pragma unroll
    for (int nf = 0; nf < 4; ++nf){
      ulonglong2 pr = mt2[pbase[nf] + ((4 * kb) ^ pm4[nf])];
      BU bu; bu.d[0] = pr.x; bu.d[1] = pr.y;
      #pragma unroll
      for (int mf = 0; mf < 4; ++mf)
        acc[mf][nf] = __builtin_amdgcn_mfma_f32_16x16x32_bf16(A[mf], bu.v, acc[mf][nf], 0, 0, 0);
    }
  }
  __syncthreads();                    // done reading n1 tile
  u64 pm[4][4];
  #pragma unroll
  for (int mf = 0; mf < 4; ++mf){
    const int fb = w * 64 + mf * 16 + g * 4;
    const float4 bb = *(const float4*)&bias_s[256 + fb];
    #pragma unroll
    for (int nf = 0; nf < 4; ++nf){
      int n = nb + nf * 16 + li;
      int nc = (n >= NN) ? NN - 1 : n;
      float4 hv = *(float4*)(h + (size_t)nc * HH + fb);
      float o0 = hv.x + acc[mf][nf][0] + bb.x;
      float o1 = hv.y + acc[mf][nf][1] + bb.y;
      float o2 = hv.z + acc[mf][nf][2] + bb.z;
      float o3 = hv.w + acc[mf][nf][3] + bb.w;
      pm[mf][nf] = pack4bf(o0, o1, o2, o3);
      if (n < NN){
        *(float4*)(h + (size_t)n * HH + fb) = make_float4(o0, o1, o2, o3);
        *(u64*)(hb + (size_t)n * HH + fb) = pm[mf][nf];
      }
    }
  }
  if (EMIT_PAB){
    #pragma unroll
    for (int nf = 0; nf < 4; ++nf){
      ulonglong2 t0; t0.x = pm[0][nf]; t0.y = pm[1][nf];
      ulonglong2 t1; t1.x = pm[2][nf]; t1.y = pm[3][nf];
      mt2[pbase[nf] + ((8 * w)     ^ pm4[nf])] = t0;
      mt2[pbase[nf] + ((8 * w + 4) ^ pm4[nf])] = t1;
    }
    __syncthreads();
    const u16* pwn = pw1n + ((size_t)(w * 4) * 64 + l) * 8;
    #pragma unroll
    for (int pass = 0; pass < 2; ++pass){
      #pragma unroll
      for (int a = 0; a < 4; ++a)
        #pragma unroll
        for (int b = 0; b < 4; ++b) acc[a][b] = (f4v){0.f,0.f,0.f,0.f};
      const u16* pwp = pwn + (size_t)(pass * 8) * 8192;
      #pragma unroll 4
      for (int kb = 0; kb < 8; ++kb){
        s8v A[4];
        #pragma unroll
        for (int mf = 0; mf < 4; ++mf) A[mf] = *(const s8v*)(pwp + (size_t)kb * 8192 + mf * 512);
        #pragma unroll
        for (int nf = 0; nf < 4; ++nf){
          ulonglong2 pr = mt2[pbase[nf] + ((4 * kb) ^ pm4[nf])];
          BU bu; bu.d[0] = pr.x; bu.d[1] = pr.y;
          #pragma unroll
          for (int mf = 0; mf < 4; ++mf)
            acc[mf][nf] = __builtin_amdgcn_mfma_f32_16x16x32_bf16(A[mf], bu.v, acc[mf][nf], 0, 0, 0);
        }
      }
      u16* dst = pass ? Pbb : Pab;
      #pragma unroll
      for (int mf = 0; mf < 4; ++mf){
        const int fb = w * 64 + mf * 16 + g * 4;
        float c0 = 0.f, c1 = 0.f, c2 = 0.f, c3 = 0.f;
        if (!pass){ c0 = b1n[fb]; c1 = b1n[fb+1]; c2 = b1n[fb+2]; c3 = b1n[fb+3]; }
        #pragma unroll
        for (int nf = 0; nf < 4; ++nf){
          int n = nb + nf * 16 + li;
          if (n < NN)
            *(u64*)(dst + (size_t)n * HH + fb) =
              pack4bf(acc[mf][nf][0] + c0, acc[mf][nf][1] + c1,
                      acc[mf][nf][2] + c2, acc[mf][nf][3] + c3);
        }
      }
    }
  }
}

// ---------------- resblock + head ----------------
__global__ __launch_bounds__(256) void final_kernel(
    const float* __restrict__ z, const float* __restrict__ rw1, const float* __restrict__ rb1,
    const float* __restrict__ rw2, const float* __restrict__ rb2,
    const float* __restrict__ hw, const float* __restrict__ hbs, float* __restrict__ out){
  __shared__ float zr[272], t1[256], t2[272];
  const int b = blockIdx.x, tid = threadIdx.x;
  for (int i = tid; i < 272; i += 256) zr[i] = z[(size_t)b * 272 + i];
  __syncthreads();
  {
    float a = rb1[tid];
    for (int k = 0; k < 272; ++k) a += zr[k] * rw1[(size_t)k * 256 + tid];
    t1[tid] = siluf(a);
  }
  __syncthreads();
  for (int i = tid; i < 272; i += 256){
    float a = rb2[i] + zr[i];
    for (int k = 0; k < 256; ++k) a += t1[k] * rw2[(size_t)k * 272 + i];
    t2[i] = a;
  }
  __syncthreads();
  for (int p = tid; p < 2000; p += 256){
    float a = hbs[p];
    for (int k = 0; k < 272; ++k) a += t2[k] * hw[(size_t)k * 2000 + p];
    out[(size_t)b * 2000 + p] = a;
  }
}

extern "C" void kernel_launch(void* const* d_in, const int* in_sizes, int n_in,
                              void* d_out, int out_size, void* d_ws, size_t ws_size,
                              hipStream_t stream){
  const float* x        = (const float*)d_in[0];
  const float* pos      = (const float*)d_in[1];
  const float* eattr    = (const float*)d_in[2];
  const float* fragl    = (const float*)d_in[3];
  const float* addf     = (const float*)d_in[4];
  const int*   ei       = (const int*)d_in[5];
  const int*   batch    = (const int*)d_in[6];
  const float* emb_in_w = (const float*)d_in[7];
  const float* emb_in_b = (const float*)d_in[8];
  const float* edge_w1  = (const float*)d_in[9];
  const float* edge_b1  = (const float*)d_in[10];
  const float* edge_w2  = (const float*)d_in[11];
  const float* edge_b2  = (const float*)d_in[12];
  const float* node_w1  = (const float*)d_in[13];
  const float* node_b1  = (const float*)d_in[14];
  const float* node_w2  = (const float*)d_in[15];
  const float* node_b2  = (const float*)d_in[16];
  const float* coord_w1 = (const float*)d_in[17];
  const float* coord_b1 = (const float*)d_in[18];
  const float* coord_w2 = (const float*)d_in[19];
  const float* emb_out_w= (const float*)d_in[20];
  const float* emb_out_b= (const float*)d_in[21];
  const float* res_w1   = (const float*)d_in[22];
  const float* res_b1   = (const float*)d_in[23];
  const float* res_w2   = (const float*)d_in[24];
  const float* res_b2   = (const float*)d_in[25];
  const float* head_w   = (const float*)d_in[26];
  const float* head_b   = (const float*)d_in[27];

  char* ws = (char*)d_ws;
  size_t off = 0;
  auto alloc = [&](size_t bytes) -> void* {
    void* p = ws + off;
    off += (bytes + 255) & ~(size_t)255;
    return p;
  };
  float*  h      = (float*)alloc((size_t)NN * HH * 4);
  float*  agg    = (float*)alloc((size_t)NN * HH * 4);
  u16*    hb     = (u16*)  alloc((size_t)NN * HH * 2);
  u16*    Pab    = (u16*)  alloc((size_t)NN * HH * 2);
  u16*    Pbb    = (u16*)  alloc((size_t)NN * HH * 2);
  float*  ho     = (float*)alloc((size_t)NN * HH * 4);
  float4* coordb = (float4*)alloc((size_t)NN * 16);
  float*  cacc   = (float*)alloc((size_t)NN * 16);
  float*  z      = (float*)alloc((size_t)BB * 272 * 4);
  u16*    packed = (u16*)  alloc((size_t)7680 * 256 * 2);
  u16*    ea_s   = (u16*)  alloc((size_t)EE * 16 * 2);
  int*    icnt   = (int*)  alloc((size_t)NN * 4);
  int*    iscan  = (int*)  alloc((size_t)NN * 4);
  int*    rstart = (int*)  alloc((size_t)NN * 4);
  int*    cursor = (int*)  alloc((size_t)NN * 4);
  int*    bsum   = (int*)  alloc((size_t)128 * 4);
  int*    bstart = (int*)  alloc((size_t)(BB + 1) * 4);
  int*    seid   = (int*)  alloc((size_t)EE * 4);
  int*    srow   = (int*)  alloc((size_t)EE * 4);
  int*    scol   = (int*)  alloc((size_t)EE * 4);
  if (off > ws_size) return;

  u16* pk_embin  = packed;
  u16* pk_embout = packed + 32768 + (size_t)4 * 466944;
  auto pk_ew1 = [&](int l){ return packed + 32768 + (size_t)l * 466944; };
  auto pk_ew2 = [&](int l){ return pk_ew1(l) + 139264; };
  auto pk_cw1 = [&](int l){ return pk_ew1(l) + 204800; };
  auto pk_nw1 = [&](int l){ return pk_ew1(l) + 270336; };
  auto pk_nw2 = [&](int l){ return pk_ew1(l) + 401408; };

  pack_kernel<<<16, 256, 0, stream>>>(emb_in_w, pk_embin, 128, 4, 0);
  for (int l = 0; l < 4; ++l){
    pack_kernel<<<68, 256, 0, stream>>>(edge_w1 + (size_t)l * 529 * 256, pk_ew1(l), 529, 17, 1);
    pack_kernel<<<32, 256, 0, stream>>>(edge_w2 + (size_t)l * 65536,     pk_ew2(l), 256, 8, 0);
    pack_kernel<<<32, 256, 0, stream>>>(coord_w1 + (size_t)l * 65536,    pk_cw1(l), 256, 8, 0);
    pack_kernel<<<64, 256, 0, stream>>>(node_w1 + (size_t)l * 131072,    pk_nw1(l), 512, 16, 0);
    pack_kernel<<<32, 256, 0, stream>>>(node_w2 + (size_t)l * 65536,     pk_nw2(l), 256, 8, 0);
  }
  pack_kernel<<<32, 256, 0, stream>>>(emb_out_w, pk_embout, 256, 8, 0);

  // ---- one-time edge sort by row + sorted eattr + per-graph ranges
  const int NB = (NN + 255) / 256;   // 79
  hipMemsetAsync(icnt,   0, (size_t)NN * 4, stream);
  hipMemsetAsync(cursor, 0, (size_t)NN * 4, stream);
  icnt_kernel<<<(EE + 255) / 256, 256, 0, stream>>>(ei, icnt);
  iscan_block<<<NB, 256, 0, stream>>>(icnt, iscan, bsum);
  iscan_top<<<1, 64, 0, stream>>>(bsum, NB);
  iscan_fix<<<NB, 256, 0, stream>>>(icnt, iscan, bsum, rstart);
  scatter_kernel<<<(EE + 255) / 256, 256, 0, stream>>>(ei, rstart, cursor, seid, srow, scol);
  sort_ea_kernel<<<(EE * 16 + 255) / 256, 256, 0, stream>>>(eattr, seid, ea_s);
  bstart_kernel<<<NB, 256, 0, stream>>>(batch, bstart);

  coord_init_kernel<<<79, 256, 0, stream>>>(pos, coordb);
  emb_in_kernel<<<313, 256, 0, stream>>>(x, pk_embin, emb_in_b, h, hb,
                                         pk_ew1(0), edge_b1, Pab, Pbb);

  for (int l = 0; l < 4; ++l){
    hipMemsetAsync(cacc, 0, (size_t)NN * 16, stream);
    hipMemsetAsync(agg,  0, (size_t)NN * HH * 4, stream);
    edge_kernel<<<5000, 512, 0, stream>>>(Pab, Pbb, coordb, srow, scol, ea_s,
        pk_ew1(l), pk_ew2(l), pk_cw1(l),
        edge_b2 + l * 256, coord_b1 + l * 256, coord_w2 + l * 256,
        agg, cacc);
    if (l < 3)
      node_pab_kernel<true><<<313, 256, 0, stream>>>(h, hb, agg, pk_nw1(l), pk_nw2(l),
          node_b1 + l * 256, node_b2 + l * 256,
          pk_ew1(l + 1), edge_b1 + (l + 1) * 256, Pab, Pbb,
          coordb, cacc, icnt);
    else
      node_pab_kernel<false><<<313, 256, 0, stream>>>(h, hb, agg, pk_nw1(l), pk_nw2(l),
          node_b1 + l * 256, node_b2 + l * 256,
          pk_ew1(0), edge_b1, Pab, Pbb,
          coordb, cacc, icnt);
  }

  emb_out_kernel<<<313, 256, 0, stream>>>(hb, pk_embout, emb_out_b, ho);
  pool_csr_kernel<<<BB * 4, 64, 0, stream>>>(ho, bstart, fragl, addf, z);
  final_kernel<<<128, 256, 0, stream>>>(z, res_w1, res_b1, res_w2, res_b2, head_w, head_b,
                                        (float*)d_out);
}